// Round 15
// baseline (395.080 us; speedup 1.0000x reference)
//
#include <hip/hip_runtime.h>
#include <hip/hip_bf16.h>

// ---------------------------------------------------------------------------
// DGL GAT (2-layer, heads=4, out=32) + WeightedSumAndMax readout.
// Round 14: recombination — r8's direct wave-uniform ssorted loads (r13's
//           __shfl broadcasts cost VALU + occupancy, agg2 77.6->82.5) KEPT
//           with r13's predicated single 8-burst tail and launch merges.
//           MFMA GEMMs / CSR / readout frozen at round-13 state.
// ---------------------------------------------------------------------------

#define HEADS 4
#define OUTF 32
#define HF 128            // HEADS*OUTF
#define IN_FEATS 74
#define PRED_DIM 128
#define NEG_SLOPE 0.2f
#define NEG_INF_ENC 0x007fffffu   // enc_f(-inf)

typedef __hip_bfloat16 bf16;
typedef __hip_bfloat162 bf16x2;
typedef __attribute__((ext_vector_type(8))) short bf16x8v;  // 8 bf16, 4 VGPRs
typedef __attribute__((ext_vector_type(4))) float f32x4v;   // MFMA C/D

__device__ __forceinline__ unsigned enc_f(float f) {
  unsigned u = __float_as_uint(f);
  return (u & 0x80000000u) ? ~u : (u | 0x80000000u);
}
__device__ __forceinline__ float dec_f(unsigned k) {
  return (k & 0x80000000u) ? __uint_as_float(k & 0x7fffffffu)
                           : __uint_as_float(~k);
}
__device__ __forceinline__ unsigned pack_bf16(float a, float b) {
  bf16x2 h = __float22bfloat162_rn(make_float2(a, b));
  return *(unsigned*)&h;
}
__device__ __forceinline__ float2 unpack_bf16(unsigned u) {
  bf16x2 h = *(bf16x2*)&u;
  return __bfloat1622float2(h);
}
__device__ __forceinline__ float lrelu(float v) {
  return fmaxf(v, NEG_SLOPE * v);
}

// ===================== MFMA node GEMM building blocks ======================
// LDS layouts (unsigned = 2 bf16). Row pad to 20 uints (40 bf16, 80B):
// bank stride 20 -> at most 2-way aliasing (free).

template <typename XT, int K>
__device__ __forceinline__ void stage_X(const XT* __restrict__ X,
                                        unsigned* Xl, int n0, int k0, int N,
                                        int tid) {
  int n = tid >> 2;            // 0..63
  int kp0 = (tid & 3) * 4;     // 0,4,8,12
  int gn = n0 + n;
  uint4 val = make_uint4(0u, 0u, 0u, 0u);
  if (gn < N) {
    if (sizeof(XT) == 4) {  // f32 input
      const float* Xf = (const float*)X;
      unsigned v[4];
#pragma unroll
      for (int j = 0; j < 4; ++j) {
        int k = k0 + (kp0 + j) * 2;
        float2 xv = make_float2(0.f, 0.f);
        if (k < K) xv = *(const float2*)&Xf[(size_t)gn * K + k];  // K even
        v[j] = pack_bf16(xv.x, xv.y);
      }
      val = make_uint4(v[0], v[1], v[2], v[3]);
    } else {  // bf16 input (K multiple of 32)
      const unsigned* Xu = (const unsigned*)X;
      val = *(const uint4*)&Xu[((size_t)gn * K + k0) / 2 + kp0];
    }
  }
  *(uint4*)&Xl[n * 20 + kp0] = val;
}

template <int K>
__device__ __forceinline__ void stage_W(const float* __restrict__ W,
                                        unsigned* Wt, int k0, int tid) {
#pragma unroll
  for (int i = 0; i < 8; ++i) {
    int c = tid & 127;
    int kp = i * 2 + (tid >> 7);
    int k = k0 + kp * 2;
    float a = 0.f, b = 0.f;
    if (k < K) {
      a = W[(size_t)k * HF + c];
      b = W[(size_t)(k + 1) * HF + c];
    }
    Wt[c * 20 + kp] = pack_bf16(a, b);
  }
}

__device__ __forceinline__ void scores_epilogue(
    const f32x4v* acc, const float* __restrict__ attn_l,
    const float* __restrict__ attn_r, float* __restrict__ el,
    float* __restrict__ er, int n0, int w, int q, int cc, int N) {
#pragma unroll
  for (int r = 0; r < 4; ++r) {
    int n = n0 + w * 16 + q * 4 + r;
    float pls[4], prs[4];
#pragma unroll
    for (int h = 0; h < 4; ++h) {
      float pl = acc[2 * h][r] * attn_l[h * 32 + cc] +
                 acc[2 * h + 1][r] * attn_l[h * 32 + 16 + cc];
      float pr = acc[2 * h][r] * attn_r[h * 32 + cc] +
                 acc[2 * h + 1][r] * attn_r[h * 32 + 16 + cc];
#pragma unroll
      for (int off = 1; off < 16; off <<= 1) {
        pl += __shfl_xor(pl, off);
        pr += __shfl_xor(pr, off);
      }
      pls[h] = pl;
      prs[h] = pr;
    }
    if (cc == 0 && n < N) {
#pragma unroll
      for (int h = 0; h < 4; ++h) {
        el[n * HEADS + h] = pls[h];
        er[n * HEADS + h] = prs[h];
      }
    }
  }
}

// Single-matrix MFMA GEMM + scores (layer 2). out bf16.
template <int K, typename XT>
__global__ __launch_bounds__(256) void mfma_gemm(
    const XT* __restrict__ X, const float* __restrict__ W,
    const float* __restrict__ attn_l, const float* __restrict__ attn_r,
    bf16* __restrict__ out, float* __restrict__ el, float* __restrict__ er,
    int N) {
  __shared__ __align__(16) unsigned Xl[64 * 20];
  __shared__ __align__(16) unsigned Wt[128 * 20];
  const int tid = threadIdx.x;
  const int w = tid >> 6;
  const int lane = tid & 63;
  const int cc = lane & 15;
  const int q = lane >> 4;
  const int n0 = blockIdx.x * 64;

  f32x4v acc[8];
#pragma unroll
  for (int t = 0; t < 8; ++t) acc[t] = f32x4v{0.f, 0.f, 0.f, 0.f};

  constexpr int KSTEPS = (K + 31) / 32;
  for (int ks = 0; ks < KSTEPS; ++ks) {
    int k0 = ks * 32;
    stage_X<XT, K>(X, Xl, n0, k0, N, tid);
    stage_W<K>(W, Wt, k0, tid);
    __syncthreads();
    bf16x8v a = *(const bf16x8v*)&Xl[(w * 16 + cc) * 20 + q * 4];
#pragma unroll
    for (int t = 0; t < 8; ++t) {
      bf16x8v b = *(const bf16x8v*)&Wt[(t * 16 + cc) * 20 + q * 4];
      acc[t] = __builtin_amdgcn_mfma_f32_16x16x32_bf16(a, b, acc[t], 0, 0, 0);
    }
    __syncthreads();
  }
#pragma unroll
  for (int r = 0; r < 4; ++r) {
    int n = n0 + w * 16 + q * 4 + r;
    if (n < N) {
#pragma unroll
      for (int t = 0; t < 8; ++t)
        out[(size_t)n * HF + t * 16 + cc] = __float2bfloat16(acc[t][r]);
    }
  }
  scores_epilogue(acc, attn_l, attn_r, el, er, n0, w, q, cc, N);
}

// Dual-matrix MFMA GEMM (layer 1): W1=fc1 -> outA + scores, W2=res1 -> outB.
template <int K>
__global__ __launch_bounds__(256) void mfma_dual(
    const float* __restrict__ X, const float* __restrict__ W1,
    const float* __restrict__ W2, const float* __restrict__ attn_l,
    const float* __restrict__ attn_r, bf16* __restrict__ outA,
    bf16* __restrict__ outB, float* __restrict__ el, float* __restrict__ er,
    int N) {
  __shared__ __align__(16) unsigned Xl[64 * 20];
  __shared__ __align__(16) unsigned Wt1[128 * 20];
  __shared__ __align__(16) unsigned Wt2[128 * 20];
  const int tid = threadIdx.x;
  const int w = tid >> 6;
  const int lane = tid & 63;
  const int cc = lane & 15;
  const int q = lane >> 4;
  const int n0 = blockIdx.x * 64;

  f32x4v acc1[8], acc2[8];
#pragma unroll
  for (int t = 0; t < 8; ++t) {
    acc1[t] = f32x4v{0.f, 0.f, 0.f, 0.f};
    acc2[t] = f32x4v{0.f, 0.f, 0.f, 0.f};
  }

  constexpr int KSTEPS = (K + 31) / 32;
  for (int ks = 0; ks < KSTEPS; ++ks) {
    int k0 = ks * 32;
    stage_X<float, K>(X, Xl, n0, k0, N, tid);
    stage_W<K>(W1, Wt1, k0, tid);
    stage_W<K>(W2, Wt2, k0, tid);
    __syncthreads();
    bf16x8v a = *(const bf16x8v*)&Xl[(w * 16 + cc) * 20 + q * 4];
#pragma unroll
    for (int t = 0; t < 8; ++t) {
      bf16x8v b1 = *(const bf16x8v*)&Wt1[(t * 16 + cc) * 20 + q * 4];
      bf16x8v b2 = *(const bf16x8v*)&Wt2[(t * 16 + cc) * 20 + q * 4];
      acc1[t] = __builtin_amdgcn_mfma_f32_16x16x32_bf16(a, b1, acc1[t], 0, 0, 0);
      acc2[t] = __builtin_amdgcn_mfma_f32_16x16x32_bf16(a, b2, acc2[t], 0, 0, 0);
    }
    __syncthreads();
  }
#pragma unroll
  for (int r = 0; r < 4; ++r) {
    int n = n0 + w * 16 + q * 4 + r;
    if (n < N) {
#pragma unroll
      for (int t = 0; t < 8; ++t) {
        outA[(size_t)n * HF + t * 16 + cc] = __float2bfloat16(acc1[t][r]);
        outB[(size_t)n * HF + t * 16 + cc] = __float2bfloat16(acc2[t][r]);
      }
    }
  }
  scores_epilogue(acc1, attn_l, attn_r, el, er, n0, w, q, cc, N);
}

// ============================ CSR build ====================================
// hist + readout-buffer init (folded).
__global__ __launch_bounds__(256) void hist_kernel(
    const int* __restrict__ dst, int* __restrict__ deg,
    float* __restrict__ hsum, unsigned* __restrict__ hmax, int E, int g32) {
  int e = blockIdx.x * 256 + threadIdx.x;
  if (e < g32) {
    hsum[e] = 0.f;
    hmax[e] = NEG_INF_ENC;
  }
  if (e < E) atomicAdd(&deg[dst[e]], 1);
}

__global__ __launch_bounds__(256) void scan1_kernel(
    const int* __restrict__ deg, int* __restrict__ row_ptr,
    int* __restrict__ bsum, int N) {
  const int base = blockIdx.x * 2048;
  const int tbase = base + threadIdx.x * 8;
  int vals[8];
  int tsum = 0;
#pragma unroll
  for (int i = 0; i < 8; ++i) {
    int idx = tbase + i;
    vals[i] = (idx < N) ? deg[idx] : 0;
    tsum += vals[i];
  }
  const int lane = threadIdx.x & 63, wv = threadIdx.x >> 6;
  int incl = tsum;
#pragma unroll
  for (int off = 1; off < 64; off <<= 1) {
    int nv = __shfl_up(incl, off);
    if (lane >= off) incl += nv;
  }
  __shared__ int wsum[4];
  if (lane == 63) wsum[wv] = incl;
  __syncthreads();
  int woff = 0;
  for (int w = 0; w < wv; ++w) woff += wsum[w];
  int run = woff + incl - tsum;
#pragma unroll
  for (int i = 0; i < 8; ++i) {
    int idx = tbase + i;
    if (idx < N) row_ptr[idx] = run;
    run += vals[i];
  }
  if (threadIdx.x == 255) bsum[blockIdx.x] = woff + incl;
}

__global__ __launch_bounds__(64) void scan2_kernel(
    const int* __restrict__ bsum, int* __restrict__ bpre, int NB) {
  const int lane = threadIdx.x;
  int running = 0;
  for (int c = 0; c < NB; c += 64) {
    int v = (c + lane < NB) ? bsum[c + lane] : 0;
    int incl = v;
#pragma unroll
    for (int off = 1; off < 64; off <<= 1) {
      int nv = __shfl_up(incl, off);
      if (lane >= off) incl += nv;
    }
    if (c + lane < NB) bpre[c + lane] = running + incl - v;
    running += __shfl(incl, 63);
  }
}

__global__ __launch_bounds__(256) void scan3_kernel(
    int* __restrict__ row_ptr, const int* __restrict__ bpre, int N, int E) {
  int t = blockIdx.x * 256 + threadIdx.x;
  if (t < N) row_ptr[t] += bpre[t >> 11];
  if (t == 0) row_ptr[N] = E;
}

__global__ __launch_bounds__(256) void scatter_kernel(
    const int* __restrict__ src, const int* __restrict__ dst,
    const int* __restrict__ row_ptr, int* __restrict__ cursor,
    int* __restrict__ ssorted, int E) {
  int e = blockIdx.x * 256 + threadIdx.x;
  if (e >= E) return;
  int d = dst[e];
  int pos = row_ptr[d] + atomicAdd(&cursor[d], 1);
  ssorted[pos] = src[e];
}

// ============ fused softmax + aggregate (single edge pass) =================
// One wave per node; lane holds cols (2*lane, 2*lane+1), head h = lane>>4.
// 8-edge straight-line bursts with DIRECT wave-uniform ssorted loads (r8);
// tail = single predicated 8-burst with clamped indices (r13).
// alpha = exp(v)/sum(exp), no max-subtraction (v bounded).

#define E8_LOAD(i, e_)                                                      \
  int s##i = ssorted[e_];                                                   \
  float xl##i = el[s##i * HEADS + h];                                       \
  unsigned fu##i = *(const unsigned*)&feat[(size_t)s##i * HF + c2];
#define E8_LOADC(i, e_)                                                     \
  int s##i = ssorted[min(e_, re - 1)];                                      \
  float xl##i = el[s##i * HEADS + h];                                       \
  unsigned fu##i = *(const unsigned*)&feat[(size_t)s##i * HF + c2];
#define E8_CALC(i)                                                          \
  {                                                                         \
    float xx = __expf(lrelu(xl##i + ern));                                  \
    float2 ff = unpack_bf16(fu##i);                                         \
    ssum += xx;                                                             \
    ax = fmaf(xx, ff.x, ax);                                                \
    ay = fmaf(xx, ff.y, ay);                                                \
  }
#define E8_CALC_PRED(i, e_)                                                 \
  {                                                                         \
    float xx = __expf(lrelu(xl##i + ern));                                  \
    xx = ((e_) + i < re) ? xx : 0.f;                                        \
    float2 ff = unpack_bf16(fu##i);                                         \
    ssum += xx;                                                             \
    ax = fmaf(xx, ff.x, ax);                                                \
    ay = fmaf(xx, ff.y, ay);                                                \
  }

#define AGG_LOOP                                                            \
  float ax = 0.f, ay = 0.f, ssum = 0.f;                                     \
  int e = rb;                                                               \
  for (; e + 8 <= re; e += 8) {                                             \
    E8_LOAD(0, e) E8_LOAD(1, e + 1) E8_LOAD(2, e + 2) E8_LOAD(3, e + 3)     \
    E8_LOAD(4, e + 4) E8_LOAD(5, e + 5) E8_LOAD(6, e + 6) E8_LOAD(7, e + 7) \
    E8_CALC(0) E8_CALC(1) E8_CALC(2) E8_CALC(3)                             \
    E8_CALC(4) E8_CALC(5) E8_CALC(6) E8_CALC(7)                             \
  }                                                                         \
  if (e < re) {                                                             \
    E8_LOADC(0, e) E8_LOADC(1, e + 1) E8_LOADC(2, e + 2)                    \
    E8_LOADC(3, e + 3) E8_LOADC(4, e + 4) E8_LOADC(5, e + 5)                \
    E8_LOADC(6, e + 6) E8_LOADC(7, e + 7)                                   \
    E8_CALC_PRED(0, e) E8_CALC_PRED(1, e) E8_CALC_PRED(2, e)                \
    E8_CALC_PRED(3, e) E8_CALC_PRED(4, e) E8_CALC_PRED(5, e)                \
    E8_CALC_PRED(6, e) E8_CALC_PRED(7, e)                                   \
  }

// Layer 1 epilogue: H[n] = elu(inv*agg + res[n] + bias)   (res, H bf16)
__global__ __launch_bounds__(256) void agg1_fused(
    const int* __restrict__ row_ptr, const int* __restrict__ ssorted,
    const float* __restrict__ el, const float* __restrict__ er,
    const bf16* __restrict__ feat, const bf16* __restrict__ res,
    bf16* __restrict__ H, const float* __restrict__ bias, int N) {
  int n = blockIdx.x * 4 + (threadIdx.x >> 6);
  if (n >= N) return;
  const int lane = threadIdx.x & 63;
  const int c2 = lane * 2, h = lane >> 4;
  const int rb = row_ptr[n], re = row_ptr[n + 1];
  const float ern = er[n * HEADS + h];

  AGG_LOOP

  float inv = 1.f / ssum;
  float2 r = unpack_bf16(*(const unsigned*)&res[(size_t)n * HF + c2]);
  float2 bi = *(const float2*)&bias[c2];
  float vx = fmaf(ax, inv, r.x + bi.x);
  float vy = fmaf(ay, inv, r.y + bi.y);
  vx = (vx > 0.f) ? vx : expm1f(vx);
  vy = (vy > 0.f) ? vy : expm1f(vy);
  *(unsigned*)&H[(size_t)n * HF + c2] = pack_bf16(vx, vy);
}

// Layer 2 epilogue: head-mean -> sigmoid gate -> readout atomics.
__global__ __launch_bounds__(256) void agg2_fused(
    const int* __restrict__ row_ptr, const int* __restrict__ ssorted,
    const float* __restrict__ el, const float* __restrict__ er,
    const bf16* __restrict__ feat, const bf16* __restrict__ h1,
    const float* __restrict__ bias, const float* __restrict__ ww,
    const float* __restrict__ wb, const int* __restrict__ gids,
    float* __restrict__ hsum, unsigned* __restrict__ hmax, int N) {
  int n = blockIdx.x * 4 + (threadIdx.x >> 6);
  if (n >= N) return;
  const int lane = threadIdx.x & 63;
  const int c2 = lane * 2, h = lane >> 4;
  const int rb = row_ptr[n], re = row_ptr[n + 1];
  const float ern = er[n * HEADS + h];

  AGG_LOOP

  float inv = 1.f / ssum;
  float2 r = unpack_bf16(*(const unsigned*)&h1[(size_t)n * HF + c2]);
  float2 bi = *(const float2*)&bias[c2];
  ax = fmaf(ax, inv, r.x + bi.x);
  ay = fmaf(ay, inv, r.y + bi.y);
  // head mean: after xor 16,32 every lane holds the sum over its 4-head class
#pragma unroll
  for (int off = 16; off < 64; off <<= 1) {
    ax += __shfl_xor(ax, off);
    ay += __shfl_xor(ay, off);
  }
  ax *= 0.25f;
  ay *= 0.25f;
  // sigmoid gate: dot(node_feats, ww) reduced over the 16-lane col groups
  int c = c2 & 31;
  float d = fmaf(ax, ww[c], ay * ww[c + 1]);
#pragma unroll
  for (int off = 1; off < 16; off <<= 1) d += __shfl_xor(d, off);
  float wv = 1.f / (1.f + __expf(-(d + wb[0])));
  if (lane < 16) {
    int g = gids[n];
    atomicAdd(&hsum[g * OUTF + c], wv * ax);
    atomicAdd(&hsum[g * OUTF + c + 1], wv * ay);
    atomicMax(&hmax[g * OUTF + c], enc_f(ax));
    atomicMax(&hmax[g * OUTF + c + 1], enc_f(ay));
  }
}

// ============================ readout tail =================================
__global__ __launch_bounds__(256) void final_gemm_kernel(
    const float* __restrict__ hsum, const unsigned* __restrict__ hmax,
    const float* __restrict__ tw, const float* __restrict__ tb,
    float* __restrict__ out, int G) {
  __shared__ float tws[64 * PRED_DIM];
  for (int i = threadIdx.x; i < 64 * PRED_DIM; i += 256) tws[i] = tw[i];
  __syncthreads();
  int g = blockIdx.x * 2 + (threadIdx.x >> 7);
  int p = threadIdx.x & 127;
  if (g >= G) return;
  float acc = tb[p];
#pragma unroll
  for (int k = 0; k < OUTF; ++k)
    acc = fmaf(hsum[g * OUTF + k], tws[k * PRED_DIM + p], acc);
#pragma unroll
  for (int k = 0; k < OUTF; ++k)
    acc = fmaf(dec_f(hmax[g * OUTF + k]), tws[(OUTF + k) * PRED_DIM + p], acc);
  out[(size_t)g * PRED_DIM + p] = acc;
}

static inline int cdiv(long long a, int b) { return (int)((a + b - 1) / b); }

extern "C" void kernel_launch(void* const* d_in, const int* in_sizes, int n_in,
                              void* d_out, int out_size, void* d_ws,
                              size_t ws_size, hipStream_t stream) {
  const float* feats   = (const float*)d_in[0];
  const int*   src     = (const int*)d_in[1];
  const int*   dst     = (const int*)d_in[2];
  const int*   gids    = (const int*)d_in[3];
  const float* fc1_w   = (const float*)d_in[4];
  const float* attn_l1 = (const float*)d_in[5];
  const float* attn_r1 = (const float*)d_in[6];
  const float* res1_w  = (const float*)d_in[7];
  const float* bias1   = (const float*)d_in[8];
  const float* fc2_w   = (const float*)d_in[9];
  const float* attn_l2 = (const float*)d_in[10];
  const float* attn_r2 = (const float*)d_in[11];
  const float* bias2   = (const float*)d_in[12];
  const float* ww      = (const float*)d_in[13];
  const float* wb      = (const float*)d_in[14];
  const float* tw      = (const float*)d_in[15];
  const float* tb      = (const float*)d_in[16];
  float* out = (float*)d_out;

  const int N = in_sizes[0] / IN_FEATS;  // 100000
  const int E = in_sizes[1];             // 900000
  const int G = out_size / PRED_DIM;     // 2048
  const int NB = cdiv(N, 2048);

  // ---- workspace layout ----
  bf16* A = (bf16*)d_ws;                      // N*128 bf16 (feat1/feat2)
  bf16* B = A + (size_t)N * HF;               // N*128 bf16 (res1)
  bf16* H = B + (size_t)N * HF;               // N*128 bf16 (h1)
  float* el = (float*)(H + (size_t)N * HF);   // N*4
  float* er = el + (size_t)N * HEADS;         // N*4
  float* hsum = er + (size_t)N * HEADS;       // G*32
  unsigned* hmax = (unsigned*)(hsum + (size_t)G * OUTF);  // G*32
  int* deg     = (int*)(hmax + (size_t)G * OUTF);  // N
  int* cursor  = deg + N;                          // N (contiguous w/ deg)
  int* row_ptr = cursor + N;                       // N+1
  int* ssorted = row_ptr + (N + 1);                // E
  int* bsum    = ssorted + E;                      // NB
  int* bpre    = bsum + NB;                        // NB

  const int gblk = cdiv(N, 64);
  const int nwblk = cdiv(N, 4);

  // ===================== CSR build =====================
  hipMemsetAsync(deg, 0, (size_t)2 * N * sizeof(int), stream);  // deg+cursor
  hist_kernel<<<cdiv(E, 256), 256, 0, stream>>>(dst, deg, hsum, hmax, E,
                                                G * OUTF);
  scan1_kernel<<<NB, 256, 0, stream>>>(deg, row_ptr, bsum, N);
  scan2_kernel<<<1, 64, 0, stream>>>(bsum, bpre, NB);
  scan3_kernel<<<cdiv(N, 256), 256, 0, stream>>>(row_ptr, bpre, N, E);
  scatter_kernel<<<cdiv(E, 256), 256, 0, stream>>>(src, dst, row_ptr, cursor,
                                                   ssorted, E);

  // ===================== Layer 1 =====================
  mfma_dual<IN_FEATS><<<gblk, 256, 0, stream>>>(
      feats, fc1_w, res1_w, attn_l1, attn_r1, A, B, el, er, N);
  agg1_fused<<<nwblk, 256, 0, stream>>>(row_ptr, ssorted, el, er, A, B, H,
                                        bias1, N);

  // ===================== Layer 2 =====================
  mfma_gemm<HF, bf16><<<gblk, 256, 0, stream>>>(
      H, fc2_w, attn_l2, attn_r2, A, el, er, N);
  agg2_fused<<<nwblk, 256, 0, stream>>>(row_ptr, ssorted, el, er, A, H, bias2,
                                        ww, wb, gids, hsum, hmax, N);

  // ===================== Readout =====================
  final_gemm_kernel<<<cdiv(G, 2), 256, 0, stream>>>(hsum, hmax, tw, tb, out, G);
}

// Round 16
// 389.893 us; speedup vs baseline: 1.0133x; 1.0133x over previous
//
#include <hip/hip_runtime.h>
#include <hip/hip_bf16.h>

// ---------------------------------------------------------------------------
// DGL GAT (2-layer, heads=4, out=32) + WeightedSumAndMax readout.
// Round 15: agg VALU trim (VALUBusy hit 77% in r14) — (1) unsigned 32-bit
//           gather offsets => saddr global_load form (saves ~4 VALU/edge of
//           64-bit address math); (2) scores pre-scaled by log2(e) in the
//           GEMM epilogue so the agg loop uses raw v_exp (exp2) without the
//           per-edge v_mul. Structure otherwise byte-identical to round 14.
// ---------------------------------------------------------------------------

#define HEADS 4
#define OUTF 32
#define HF 128            // HEADS*OUTF
#define IN_FEATS 74
#define PRED_DIM 128
#define NEG_SLOPE 0.2f
#define NEG_INF_ENC 0x007fffffu   // enc_f(-inf)
#define LOG2E 1.4426950408889634f

typedef __hip_bfloat16 bf16;
typedef __hip_bfloat162 bf16x2;
typedef __attribute__((ext_vector_type(8))) short bf16x8v;  // 8 bf16, 4 VGPRs
typedef __attribute__((ext_vector_type(4))) float f32x4v;   // MFMA C/D

__device__ __forceinline__ unsigned enc_f(float f) {
  unsigned u = __float_as_uint(f);
  return (u & 0x80000000u) ? ~u : (u | 0x80000000u);
}
__device__ __forceinline__ float dec_f(unsigned k) {
  return (k & 0x80000000u) ? __uint_as_float(k & 0x7fffffffu)
                           : __uint_as_float(~k);
}
__device__ __forceinline__ unsigned pack_bf16(float a, float b) {
  bf16x2 h = __float22bfloat162_rn(make_float2(a, b));
  return *(unsigned*)&h;
}
__device__ __forceinline__ float2 unpack_bf16(unsigned u) {
  bf16x2 h = *(bf16x2*)&u;
  return __bfloat1622float2(h);
}
__device__ __forceinline__ float lrelu(float v) {
  return fmaxf(v, NEG_SLOPE * v);
}

// ===================== MFMA node GEMM building blocks ======================
// LDS layouts (unsigned = 2 bf16). Row pad to 20 uints (40 bf16, 80B):
// bank stride 20 -> at most 2-way aliasing (free).

template <typename XT, int K>
__device__ __forceinline__ void stage_X(const XT* __restrict__ X,
                                        unsigned* Xl, int n0, int k0, int N,
                                        int tid) {
  int n = tid >> 2;            // 0..63
  int kp0 = (tid & 3) * 4;     // 0,4,8,12
  int gn = n0 + n;
  uint4 val = make_uint4(0u, 0u, 0u, 0u);
  if (gn < N) {
    if (sizeof(XT) == 4) {  // f32 input
      const float* Xf = (const float*)X;
      unsigned v[4];
#pragma unroll
      for (int j = 0; j < 4; ++j) {
        int k = k0 + (kp0 + j) * 2;
        float2 xv = make_float2(0.f, 0.f);
        if (k < K) xv = *(const float2*)&Xf[(size_t)gn * K + k];  // K even
        v[j] = pack_bf16(xv.x, xv.y);
      }
      val = make_uint4(v[0], v[1], v[2], v[3]);
    } else {  // bf16 input (K multiple of 32)
      const unsigned* Xu = (const unsigned*)X;
      val = *(const uint4*)&Xu[((size_t)gn * K + k0) / 2 + kp0];
    }
  }
  *(uint4*)&Xl[n * 20 + kp0] = val;
}

template <int K>
__device__ __forceinline__ void stage_W(const float* __restrict__ W,
                                        unsigned* Wt, int k0, int tid) {
#pragma unroll
  for (int i = 0; i < 8; ++i) {
    int c = tid & 127;
    int kp = i * 2 + (tid >> 7);
    int k = k0 + kp * 2;
    float a = 0.f, b = 0.f;
    if (k < K) {
      a = W[(size_t)k * HF + c];
      b = W[(size_t)(k + 1) * HF + c];
    }
    Wt[c * 20 + kp] = pack_bf16(a, b);
  }
}

// Scores epilogue: stores el/er PRE-SCALED by log2(e) so the agg loop can
// use raw v_exp (base-2). lrelu commutes with the positive scale, and
// alpha = 2^(lrelu(v)*log2e) / sum(...) == exp-softmax exactly.
__device__ __forceinline__ void scores_epilogue(
    const f32x4v* acc, const float* __restrict__ attn_l,
    const float* __restrict__ attn_r, float* __restrict__ el,
    float* __restrict__ er, int n0, int w, int q, int cc, int N) {
#pragma unroll
  for (int r = 0; r < 4; ++r) {
    int n = n0 + w * 16 + q * 4 + r;
    float pls[4], prs[4];
#pragma unroll
    for (int h = 0; h < 4; ++h) {
      float pl = acc[2 * h][r] * attn_l[h * 32 + cc] +
                 acc[2 * h + 1][r] * attn_l[h * 32 + 16 + cc];
      float pr = acc[2 * h][r] * attn_r[h * 32 + cc] +
                 acc[2 * h + 1][r] * attn_r[h * 32 + 16 + cc];
#pragma unroll
      for (int off = 1; off < 16; off <<= 1) {
        pl += __shfl_xor(pl, off);
        pr += __shfl_xor(pr, off);
      }
      pls[h] = pl;
      prs[h] = pr;
    }
    if (cc == 0 && n < N) {
#pragma unroll
      for (int h = 0; h < 4; ++h) {
        el[n * HEADS + h] = pls[h] * LOG2E;
        er[n * HEADS + h] = prs[h] * LOG2E;
      }
    }
  }
}

// Single-matrix MFMA GEMM + scores (layer 2). out bf16.
template <int K, typename XT>
__global__ __launch_bounds__(256) void mfma_gemm(
    const XT* __restrict__ X, const float* __restrict__ W,
    const float* __restrict__ attn_l, const float* __restrict__ attn_r,
    bf16* __restrict__ out, float* __restrict__ el, float* __restrict__ er,
    int N) {
  __shared__ __align__(16) unsigned Xl[64 * 20];
  __shared__ __align__(16) unsigned Wt[128 * 20];
  const int tid = threadIdx.x;
  const int w = tid >> 6;
  const int lane = tid & 63;
  const int cc = lane & 15;
  const int q = lane >> 4;
  const int n0 = blockIdx.x * 64;

  f32x4v acc[8];
#pragma unroll
  for (int t = 0; t < 8; ++t) acc[t] = f32x4v{0.f, 0.f, 0.f, 0.f};

  constexpr int KSTEPS = (K + 31) / 32;
  for (int ks = 0; ks < KSTEPS; ++ks) {
    int k0 = ks * 32;
    stage_X<XT, K>(X, Xl, n0, k0, N, tid);
    stage_W<K>(W, Wt, k0, tid);
    __syncthreads();
    bf16x8v a = *(const bf16x8v*)&Xl[(w * 16 + cc) * 20 + q * 4];
#pragma unroll
    for (int t = 0; t < 8; ++t) {
      bf16x8v b = *(const bf16x8v*)&Wt[(t * 16 + cc) * 20 + q * 4];
      acc[t] = __builtin_amdgcn_mfma_f32_16x16x32_bf16(a, b, acc[t], 0, 0, 0);
    }
    __syncthreads();
  }
#pragma unroll
  for (int r = 0; r < 4; ++r) {
    int n = n0 + w * 16 + q * 4 + r;
    if (n < N) {
#pragma unroll
      for (int t = 0; t < 8; ++t)
        out[(size_t)n * HF + t * 16 + cc] = __float2bfloat16(acc[t][r]);
    }
  }
  scores_epilogue(acc, attn_l, attn_r, el, er, n0, w, q, cc, N);
}

// Dual-matrix MFMA GEMM (layer 1): W1=fc1 -> outA + scores, W2=res1 -> outB.
template <int K>
__global__ __launch_bounds__(256) void mfma_dual(
    const float* __restrict__ X, const float* __restrict__ W1,
    const float* __restrict__ W2, const float* __restrict__ attn_l,
    const float* __restrict__ attn_r, bf16* __restrict__ outA,
    bf16* __restrict__ outB, float* __restrict__ el, float* __restrict__ er,
    int N) {
  __shared__ __align__(16) unsigned Xl[64 * 20];
  __shared__ __align__(16) unsigned Wt1[128 * 20];
  __shared__ __align__(16) unsigned Wt2[128 * 20];
  const int tid = threadIdx.x;
  const int w = tid >> 6;
  const int lane = tid & 63;
  const int cc = lane & 15;
  const int q = lane >> 4;
  const int n0 = blockIdx.x * 64;

  f32x4v acc1[8], acc2[8];
#pragma unroll
  for (int t = 0; t < 8; ++t) {
    acc1[t] = f32x4v{0.f, 0.f, 0.f, 0.f};
    acc2[t] = f32x4v{0.f, 0.f, 0.f, 0.f};
  }

  constexpr int KSTEPS = (K + 31) / 32;
  for (int ks = 0; ks < KSTEPS; ++ks) {
    int k0 = ks * 32;
    stage_X<float, K>(X, Xl, n0, k0, N, tid);
    stage_W<K>(W1, Wt1, k0, tid);
    stage_W<K>(W2, Wt2, k0, tid);
    __syncthreads();
    bf16x8v a = *(const bf16x8v*)&Xl[(w * 16 + cc) * 20 + q * 4];
#pragma unroll
    for (int t = 0; t < 8; ++t) {
      bf16x8v b1 = *(const bf16x8v*)&Wt1[(t * 16 + cc) * 20 + q * 4];
      bf16x8v b2 = *(const bf16x8v*)&Wt2[(t * 16 + cc) * 20 + q * 4];
      acc1[t] = __builtin_amdgcn_mfma_f32_16x16x32_bf16(a, b1, acc1[t], 0, 0, 0);
      acc2[t] = __builtin_amdgcn_mfma_f32_16x16x32_bf16(a, b2, acc2[t], 0, 0, 0);
    }
    __syncthreads();
  }
#pragma unroll
  for (int r = 0; r < 4; ++r) {
    int n = n0 + w * 16 + q * 4 + r;
    if (n < N) {
#pragma unroll
      for (int t = 0; t < 8; ++t) {
        outA[(size_t)n * HF + t * 16 + cc] = __float2bfloat16(acc1[t][r]);
        outB[(size_t)n * HF + t * 16 + cc] = __float2bfloat16(acc2[t][r]);
      }
    }
  }
  scores_epilogue(acc1, attn_l, attn_r, el, er, n0, w, q, cc, N);
}

// ============================ CSR build ====================================
// hist + readout-buffer init (folded).
__global__ __launch_bounds__(256) void hist_kernel(
    const int* __restrict__ dst, int* __restrict__ deg,
    float* __restrict__ hsum, unsigned* __restrict__ hmax, int E, int g32) {
  int e = blockIdx.x * 256 + threadIdx.x;
  if (e < g32) {
    hsum[e] = 0.f;
    hmax[e] = NEG_INF_ENC;
  }
  if (e < E) atomicAdd(&deg[dst[e]], 1);
}

__global__ __launch_bounds__(256) void scan1_kernel(
    const int* __restrict__ deg, int* __restrict__ row_ptr,
    int* __restrict__ bsum, int N) {
  const int base = blockIdx.x * 2048;
  const int tbase = base + threadIdx.x * 8;
  int vals[8];
  int tsum = 0;
#pragma unroll
  for (int i = 0; i < 8; ++i) {
    int idx = tbase + i;
    vals[i] = (idx < N) ? deg[idx] : 0;
    tsum += vals[i];
  }
  const int lane = threadIdx.x & 63, wv = threadIdx.x >> 6;
  int incl = tsum;
#pragma unroll
  for (int off = 1; off < 64; off <<= 1) {
    int nv = __shfl_up(incl, off);
    if (lane >= off) incl += nv;
  }
  __shared__ int wsum[4];
  if (lane == 63) wsum[wv] = incl;
  __syncthreads();
  int woff = 0;
  for (int w = 0; w < wv; ++w) woff += wsum[w];
  int run = woff + incl - tsum;
#pragma unroll
  for (int i = 0; i < 8; ++i) {
    int idx = tbase + i;
    if (idx < N) row_ptr[idx] = run;
    run += vals[i];
  }
  if (threadIdx.x == 255) bsum[blockIdx.x] = woff + incl;
}

__global__ __launch_bounds__(64) void scan2_kernel(
    const int* __restrict__ bsum, int* __restrict__ bpre, int NB) {
  const int lane = threadIdx.x;
  int running = 0;
  for (int c = 0; c < NB; c += 64) {
    int v = (c + lane < NB) ? bsum[c + lane] : 0;
    int incl = v;
#pragma unroll
    for (int off = 1; off < 64; off <<= 1) {
      int nv = __shfl_up(incl, off);
      if (lane >= off) incl += nv;
    }
    if (c + lane < NB) bpre[c + lane] = running + incl - v;
    running += __shfl(incl, 63);
  }
}

__global__ __launch_bounds__(256) void scan3_kernel(
    int* __restrict__ row_ptr, const int* __restrict__ bpre, int N, int E) {
  int t = blockIdx.x * 256 + threadIdx.x;
  if (t < N) row_ptr[t] += bpre[t >> 11];
  if (t == 0) row_ptr[N] = E;
}

__global__ __launch_bounds__(256) void scatter_kernel(
    const int* __restrict__ src, const int* __restrict__ dst,
    const int* __restrict__ row_ptr, int* __restrict__ cursor,
    int* __restrict__ ssorted, int E) {
  int e = blockIdx.x * 256 + threadIdx.x;
  if (e >= E) return;
  int d = dst[e];
  int pos = row_ptr[d] + atomicAdd(&cursor[d], 1);
  ssorted[pos] = src[e];
}

// ============ fused softmax + aggregate (single edge pass) =================
// One wave per node; lane holds cols (2*lane, 2*lane+1), head h = lane>>4.
// 8-edge straight-line bursts, direct wave-uniform ssorted loads, predicated
// clamped 8-burst tail. Gathers use UNSIGNED 32-bit offsets (saddr form).
// alpha = exp2(lrelu(v'))/sum (v' pre-scaled by log2e), no max-subtraction.

#define E8_LOAD(i, e_)                                                      \
  int s##i = ssorted[e_];                                                   \
  float xl##i = el[(unsigned)s##i * HEADS + h];                             \
  unsigned fu##i = *(const unsigned*)&feat[(unsigned)s##i * HF + c2];
#define E8_LOADC(i, e_)                                                     \
  int s##i = ssorted[min(e_, re - 1)];                                      \
  float xl##i = el[(unsigned)s##i * HEADS + h];                             \
  unsigned fu##i = *(const unsigned*)&feat[(unsigned)s##i * HF + c2];
#define E8_CALC(i)                                                          \
  {                                                                         \
    float xx = __builtin_amdgcn_exp2f(lrelu(xl##i + ern));                  \
    float2 ff = unpack_bf16(fu##i);                                         \
    ssum += xx;                                                             \
    ax = fmaf(xx, ff.x, ax);                                                \
    ay = fmaf(xx, ff.y, ay);                                                \
  }
#define E8_CALC_PRED(i, e_)                                                 \
  {                                                                         \
    float xx = __builtin_amdgcn_exp2f(lrelu(xl##i + ern));                  \
    xx = ((e_) + i < re) ? xx : 0.f;                                        \
    float2 ff = unpack_bf16(fu##i);                                         \
    ssum += xx;                                                             \
    ax = fmaf(xx, ff.x, ax);                                                \
    ay = fmaf(xx, ff.y, ay);                                                \
  }

#define AGG_LOOP                                                            \
  float ax = 0.f, ay = 0.f, ssum = 0.f;                                     \
  int e = rb;                                                               \
  for (; e + 8 <= re; e += 8) {                                             \
    E8_LOAD(0, e) E8_LOAD(1, e + 1) E8_LOAD(2, e + 2) E8_LOAD(3, e + 3)     \
    E8_LOAD(4, e + 4) E8_LOAD(5, e + 5) E8_LOAD(6, e + 6) E8_LOAD(7, e + 7) \
    E8_CALC(0) E8_CALC(1) E8_CALC(2) E8_CALC(3)                             \
    E8_CALC(4) E8_CALC(5) E8_CALC(6) E8_CALC(7)                             \
  }                                                                         \
  if (e < re) {                                                             \
    E8_LOADC(0, e) E8_LOADC(1, e + 1) E8_LOADC(2, e + 2)                    \
    E8_LOADC(3, e + 3) E8_LOADC(4, e + 4) E8_LOADC(5, e + 5)                \
    E8_LOADC(6, e + 6) E8_LOADC(7, e + 7)                                   \
    E8_CALC_PRED(0, e) E8_CALC_PRED(1, e) E8_CALC_PRED(2, e)                \
    E8_CALC_PRED(3, e) E8_CALC_PRED(4, e) E8_CALC_PRED(5, e)                \
    E8_CALC_PRED(6, e) E8_CALC_PRED(7, e)                                   \
  }

// Layer 1 epilogue: H[n] = elu(inv*agg + res[n] + bias)   (res, H bf16)
__global__ __launch_bounds__(256) void agg1_fused(
    const int* __restrict__ row_ptr, const int* __restrict__ ssorted,
    const float* __restrict__ el, const float* __restrict__ er,
    const bf16* __restrict__ feat, const bf16* __restrict__ res,
    bf16* __restrict__ H, const float* __restrict__ bias, int N) {
  int n = blockIdx.x * 4 + (threadIdx.x >> 6);
  if (n >= N) return;
  const int lane = threadIdx.x & 63;
  const int c2 = lane * 2, h = lane >> 4;
  const int rb = row_ptr[n], re = row_ptr[n + 1];
  const float ern = er[(unsigned)n * HEADS + h];

  AGG_LOOP

  float inv = 1.f / ssum;
  float2 r = unpack_bf16(*(const unsigned*)&res[(unsigned)n * HF + c2]);
  float2 bi = *(const float2*)&bias[c2];
  float vx = fmaf(ax, inv, r.x + bi.x);
  float vy = fmaf(ay, inv, r.y + bi.y);
  vx = (vx > 0.f) ? vx : expm1f(vx);
  vy = (vy > 0.f) ? vy : expm1f(vy);
  *(unsigned*)&H[(unsigned)n * HF + c2] = pack_bf16(vx, vy);
}

// Layer 2 epilogue: head-mean -> sigmoid gate -> readout atomics.
__global__ __launch_bounds__(256) void agg2_fused(
    const int* __restrict__ row_ptr, const int* __restrict__ ssorted,
    const float* __restrict__ el, const float* __restrict__ er,
    const bf16* __restrict__ feat, const bf16* __restrict__ h1,
    const float* __restrict__ bias, const float* __restrict__ ww,
    const float* __restrict__ wb, const int* __restrict__ gids,
    float* __restrict__ hsum, unsigned* __restrict__ hmax, int N) {
  int n = blockIdx.x * 4 + (threadIdx.x >> 6);
  if (n >= N) return;
  const int lane = threadIdx.x & 63;
  const int c2 = lane * 2, h = lane >> 4;
  const int rb = row_ptr[n], re = row_ptr[n + 1];
  const float ern = er[(unsigned)n * HEADS + h];

  AGG_LOOP

  float inv = 1.f / ssum;
  float2 r = unpack_bf16(*(const unsigned*)&h1[(unsigned)n * HF + c2]);
  float2 bi = *(const float2*)&bias[c2];
  ax = fmaf(ax, inv, r.x + bi.x);
  ay = fmaf(ay, inv, r.y + bi.y);
  // head mean: after xor 16,32 every lane holds the sum over its 4-head class
#pragma unroll
  for (int off = 16; off < 64; off <<= 1) {
    ax += __shfl_xor(ax, off);
    ay += __shfl_xor(ay, off);
  }
  ax *= 0.25f;
  ay *= 0.25f;
  // sigmoid gate: dot(node_feats, ww) reduced over the 16-lane col groups
  int c = c2 & 31;
  float d = fmaf(ax, ww[c], ay * ww[c + 1]);
#pragma unroll
  for (int off = 1; off < 16; off <<= 1) d += __shfl_xor(d, off);
  float wv = 1.f / (1.f + __expf(-(d + wb[0])));
  if (lane < 16) {
    int g = gids[n];
    atomicAdd(&hsum[g * OUTF + c], wv * ax);
    atomicAdd(&hsum[g * OUTF + c + 1], wv * ay);
    atomicMax(&hmax[g * OUTF + c], enc_f(ax));
    atomicMax(&hmax[g * OUTF + c + 1], enc_f(ay));
  }
}

// ============================ readout tail =================================
__global__ __launch_bounds__(256) void final_gemm_kernel(
    const float* __restrict__ hsum, const unsigned* __restrict__ hmax,
    const float* __restrict__ tw, const float* __restrict__ tb,
    float* __restrict__ out, int G) {
  __shared__ float tws[64 * PRED_DIM];
  for (int i = threadIdx.x; i < 64 * PRED_DIM; i += 256) tws[i] = tw[i];
  __syncthreads();
  int g = blockIdx.x * 2 + (threadIdx.x >> 7);
  int p = threadIdx.x & 127;
  if (g >= G) return;
  float acc = tb[p];
#pragma unroll
  for (int k = 0; k < OUTF; ++k)
    acc = fmaf(hsum[g * OUTF + k], tws[k * PRED_DIM + p], acc);
#pragma unroll
  for (int k = 0; k < OUTF; ++k)
    acc = fmaf(dec_f(hmax[g * OUTF + k]), tws[(OUTF + k) * PRED_DIM + p], acc);
  out[(size_t)g * PRED_DIM + p] = acc;
}

static inline int cdiv(long long a, int b) { return (int)((a + b - 1) / b); }

extern "C" void kernel_launch(void* const* d_in, const int* in_sizes, int n_in,
                              void* d_out, int out_size, void* d_ws,
                              size_t ws_size, hipStream_t stream) {
  const float* feats   = (const float*)d_in[0];
  const int*   src     = (const int*)d_in[1];
  const int*   dst     = (const int*)d_in[2];
  const int*   gids    = (const int*)d_in[3];
  const float* fc1_w   = (const float*)d_in[4];
  const float* attn_l1 = (const float*)d_in[5];
  const float* attn_r1 = (const float*)d_in[6];
  const float* res1_w  = (const float*)d_in[7];
  const float* bias1   = (const float*)d_in[8];
  const float* fc2_w   = (const float*)d_in[9];
  const float* attn_l2 = (const float*)d_in[10];
  const float* attn_r2 = (const float*)d_in[11];
  const float* bias2   = (const float*)d_in[12];
  const float* ww      = (const float*)d_in[13];
  const float* wb      = (const float*)d_in[14];
  const float* tw      = (const float*)d_in[15];
  const float* tb      = (const float*)d_in[16];
  float* out = (float*)d_out;

  const int N = in_sizes[0] / IN_FEATS;  // 100000
  const int E = in_sizes[1];             // 900000
  const int G = out_size / PRED_DIM;     // 2048
  const int NB = cdiv(N, 2048);

  // ---- workspace layout ----
  bf16* A = (bf16*)d_ws;                      // N*128 bf16 (feat1/feat2)
  bf16* B = A + (size_t)N * HF;               // N*128 bf16 (res1)
  bf16* H = B + (size_t)N * HF;               // N*128 bf16 (h1)
  float* el = (float*)(H + (size_t)N * HF);   // N*4
  float* er = el + (size_t)N * HEADS;         // N*4
  float* hsum = er + (size_t)N * HEADS;       // G*32
  unsigned* hmax = (unsigned*)(hsum + (size_t)G * OUTF);  // G*32
  int* deg     = (int*)(hmax + (size_t)G * OUTF);  // N
  int* cursor  = deg + N;                          // N (contiguous w/ deg)
  int* row_ptr = cursor + N;                       // N+1
  int* ssorted = row_ptr + (N + 1);                // E
  int* bsum    = ssorted + E;                      // NB
  int* bpre    = bsum + NB;                        // NB

  const int gblk = cdiv(N, 64);
  const int nwblk = cdiv(N, 4);

  // ===================== CSR build =====================
  hipMemsetAsync(deg, 0, (size_t)2 * N * sizeof(int), stream);  // deg+cursor
  hist_kernel<<<cdiv(E, 256), 256, 0, stream>>>(dst, deg, hsum, hmax, E,
                                                G * OUTF);
  scan1_kernel<<<NB, 256, 0, stream>>>(deg, row_ptr, bsum, N);
  scan2_kernel<<<1, 64, 0, stream>>>(bsum, bpre, NB);
  scan3_kernel<<<cdiv(N, 256), 256, 0, stream>>>(row_ptr, bpre, N, E);
  scatter_kernel<<<cdiv(E, 256), 256, 0, stream>>>(src, dst, row_ptr, cursor,
                                                   ssorted, E);

  // ===================== Layer 1 =====================
  mfma_dual<IN_FEATS><<<gblk, 256, 0, stream>>>(
      feats, fc1_w, res1_w, attn_l1, attn_r1, A, B, el, er, N);
  agg1_fused<<<nwblk, 256, 0, stream>>>(row_ptr, ssorted, el, er, A, B, H,
                                        bias1, N);

  // ===================== Layer 2 =====================
  mfma_gemm<HF, bf16><<<gblk, 256, 0, stream>>>(
      H, fc2_w, attn_l2, attn_r2, A, el, er, N);
  agg2_fused<<<nwblk, 256, 0, stream>>>(row_ptr, ssorted, el, er, A, H, bias2,
                                        ww, wb, gids, hsum, hmax, N);

  // ===================== Readout =====================
  final_gemm_kernel<<<cdiv(G, 2), 256, 0, stream>>>(hsum, hmax, tw, tb, out, G);
}

// Round 17
// 378.159 us; speedup vs baseline: 1.0447x; 1.0310x over previous
//
#include <hip/hip_runtime.h>
#include <hip/hip_bf16.h>

// ---------------------------------------------------------------------------
// DGL GAT (2-layer, heads=4, out=32) + WeightedSumAndMax readout.
// Round 16: mid-tier cleanup — (1) hist's atomic return value persisted as
//           rank[e] => scatter is atomic-free (was a 2nd round of 900K
//           atomics); cursor array deleted. (2) one-shot prep_w kernel
//           pre-packs all 3 weight matrices to bf16 [col][kpair] so GEMM
//           staging is uint copies (no f32 reads / cvt per block).
//           Agg kernels byte-identical to round 15.
// ---------------------------------------------------------------------------

#define HEADS 4
#define OUTF 32
#define HF 128            // HEADS*OUTF
#define IN_FEATS 74
#define PRED_DIM 128
#define NEG_SLOPE 0.2f
#define NEG_INF_ENC 0x007fffffu   // enc_f(-inf)
#define LOG2E 1.4426950408889634f
#define KP1 48            // kpairs for K=74 (padded to 96)
#define KP2 64            // kpairs for K=128

typedef __hip_bfloat16 bf16;
typedef __hip_bfloat162 bf16x2;
typedef __attribute__((ext_vector_type(8))) short bf16x8v;  // 8 bf16, 4 VGPRs
typedef __attribute__((ext_vector_type(4))) float f32x4v;   // MFMA C/D

__device__ __forceinline__ unsigned enc_f(float f) {
  unsigned u = __float_as_uint(f);
  return (u & 0x80000000u) ? ~u : (u | 0x80000000u);
}
__device__ __forceinline__ float dec_f(unsigned k) {
  return (k & 0x80000000u) ? __uint_as_float(k & 0x7fffffffu)
                           : __uint_as_float(~k);
}
__device__ __forceinline__ unsigned pack_bf16(float a, float b) {
  bf16x2 h = __float22bfloat162_rn(make_float2(a, b));
  return *(unsigned*)&h;
}
__device__ __forceinline__ float2 unpack_bf16(unsigned u) {
  bf16x2 h = *(bf16x2*)&u;
  return __bfloat1622float2(h);
}
__device__ __forceinline__ float lrelu(float v) {
  return fmaxf(v, NEG_SLOPE * v);
}

// ================= weight pre-pack (once per call, 56 blocks) ==============
// f32 [k][c] -> bf16-pair [c][kpair], zero-padded to KP kpairs.
__global__ __launch_bounds__(256) void prep_w(
    const float* __restrict__ W1, const float* __restrict__ W2,
    const float* __restrict__ W3, unsigned* __restrict__ WT1,
    unsigned* __restrict__ WT2, unsigned* __restrict__ WT3) {
  int t = blockIdx.x * 256 + threadIdx.x;
  if (t < 128 * KP1) {
    int c = t / KP1, kp = t % KP1;
    int k = kp * 2;
    float a1 = (k < IN_FEATS) ? W1[k * HF + c] : 0.f;
    float b1 = (k + 1 < IN_FEATS) ? W1[(k + 1) * HF + c] : 0.f;
    float a2 = (k < IN_FEATS) ? W2[k * HF + c] : 0.f;
    float b2 = (k + 1 < IN_FEATS) ? W2[(k + 1) * HF + c] : 0.f;
    WT1[t] = pack_bf16(a1, b1);
    WT2[t] = pack_bf16(a2, b2);
  } else {
    int u = t - 128 * KP1;
    if (u < 128 * KP2) {
      int c = u / KP2, kp = u % KP2;
      int k = kp * 2;
      WT3[u] = pack_bf16(W3[k * HF + c], W3[(k + 1) * HF + c]);
    }
  }
}

// ===================== MFMA node GEMM building blocks ======================
// LDS rows padded to 20 uints (80B): bank stride 20 -> 2-way max (free).

template <typename XT, int K>
__device__ __forceinline__ void stage_X(const XT* __restrict__ X,
                                        unsigned* Xl, int n0, int k0, int N,
                                        int tid) {
  int n = tid >> 2;            // 0..63
  int kp0 = (tid & 3) * 4;     // 0,4,8,12
  int gn = n0 + n;
  uint4 val = make_uint4(0u, 0u, 0u, 0u);
  if (gn < N) {
    if (sizeof(XT) == 4) {  // f32 input
      const float* Xf = (const float*)X;
      unsigned v[4];
#pragma unroll
      for (int j = 0; j < 4; ++j) {
        int k = k0 + (kp0 + j) * 2;
        float2 xv = make_float2(0.f, 0.f);
        if (k < K) xv = *(const float2*)&Xf[(size_t)gn * K + k];  // K even
        v[j] = pack_bf16(xv.x, xv.y);
      }
      val = make_uint4(v[0], v[1], v[2], v[3]);
    } else {  // bf16 input (K multiple of 32)
      const unsigned* Xu = (const unsigned*)X;
      val = *(const uint4*)&Xu[((size_t)gn * K + k0) / 2 + kp0];
    }
  }
  *(uint4*)&Xl[n * 20 + kp0] = val;
}

// Copy pre-packed weight tile (128 cols x 16 kpairs) into LDS.
template <int KP>
__device__ __forceinline__ void stage_Wpre(const unsigned* __restrict__ WT,
                                           unsigned* Wt, int ks, int tid) {
#pragma unroll
  for (int i = 0; i < 8; ++i) {
    int c = tid & 127;
    int kp = i * 2 + (tid >> 7);
    Wt[c * 20 + kp] = WT[c * KP + ks * 16 + kp];
  }
}

// Scores epilogue: stores el/er PRE-SCALED by log2(e) (agg uses raw exp2).
__device__ __forceinline__ void scores_epilogue(
    const f32x4v* acc, const float* __restrict__ attn_l,
    const float* __restrict__ attn_r, float* __restrict__ el,
    float* __restrict__ er, int n0, int w, int q, int cc, int N) {
#pragma unroll
  for (int r = 0; r < 4; ++r) {
    int n = n0 + w * 16 + q * 4 + r;
    float pls[4], prs[4];
#pragma unroll
    for (int h = 0; h < 4; ++h) {
      float pl = acc[2 * h][r] * attn_l[h * 32 + cc] +
                 acc[2 * h + 1][r] * attn_l[h * 32 + 16 + cc];
      float pr = acc[2 * h][r] * attn_r[h * 32 + cc] +
                 acc[2 * h + 1][r] * attn_r[h * 32 + 16 + cc];
#pragma unroll
      for (int off = 1; off < 16; off <<= 1) {
        pl += __shfl_xor(pl, off);
        pr += __shfl_xor(pr, off);
      }
      pls[h] = pl;
      prs[h] = pr;
    }
    if (cc == 0 && n < N) {
#pragma unroll
      for (int h = 0; h < 4; ++h) {
        el[n * HEADS + h] = pls[h] * LOG2E;
        er[n * HEADS + h] = prs[h] * LOG2E;
      }
    }
  }
}

// Single-matrix MFMA GEMM + scores (layer 2). out bf16.
template <int K, int KP, typename XT>
__global__ __launch_bounds__(256) void mfma_gemm(
    const XT* __restrict__ X, const unsigned* __restrict__ WT,
    const float* __restrict__ attn_l, const float* __restrict__ attn_r,
    bf16* __restrict__ out, float* __restrict__ el, float* __restrict__ er,
    int N) {
  __shared__ __align__(16) unsigned Xl[64 * 20];
  __shared__ __align__(16) unsigned Wt[128 * 20];
  const int tid = threadIdx.x;
  const int w = tid >> 6;
  const int lane = tid & 63;
  const int cc = lane & 15;
  const int q = lane >> 4;
  const int n0 = blockIdx.x * 64;

  f32x4v acc[8];
#pragma unroll
  for (int t = 0; t < 8; ++t) acc[t] = f32x4v{0.f, 0.f, 0.f, 0.f};

  constexpr int KSTEPS = (K + 31) / 32;
  for (int ks = 0; ks < KSTEPS; ++ks) {
    int k0 = ks * 32;
    stage_X<XT, K>(X, Xl, n0, k0, N, tid);
    stage_Wpre<KP>(WT, Wt, ks, tid);
    __syncthreads();
    bf16x8v a = *(const bf16x8v*)&Xl[(w * 16 + cc) * 20 + q * 4];
#pragma unroll
    for (int t = 0; t < 8; ++t) {
      bf16x8v b = *(const bf16x8v*)&Wt[(t * 16 + cc) * 20 + q * 4];
      acc[t] = __builtin_amdgcn_mfma_f32_16x16x32_bf16(a, b, acc[t], 0, 0, 0);
    }
    __syncthreads();
  }
#pragma unroll
  for (int r = 0; r < 4; ++r) {
    int n = n0 + w * 16 + q * 4 + r;
    if (n < N) {
#pragma unroll
      for (int t = 0; t < 8; ++t)
        out[(size_t)n * HF + t * 16 + cc] = __float2bfloat16(acc[t][r]);
    }
  }
  scores_epilogue(acc, attn_l, attn_r, el, er, n0, w, q, cc, N);
}

// Dual-matrix MFMA GEMM (layer 1): WT1=fc1 -> outA + scores, WT2=res1 -> outB.
template <int K, int KP>
__global__ __launch_bounds__(256) void mfma_dual(
    const float* __restrict__ X, const unsigned* __restrict__ WT1,
    const unsigned* __restrict__ WT2, const float* __restrict__ attn_l,
    const float* __restrict__ attn_r, bf16* __restrict__ outA,
    bf16* __restrict__ outB, float* __restrict__ el, float* __restrict__ er,
    int N) {
  __shared__ __align__(16) unsigned Xl[64 * 20];
  __shared__ __align__(16) unsigned Wt1[128 * 20];
  __shared__ __align__(16) unsigned Wt2[128 * 20];
  const int tid = threadIdx.x;
  const int w = tid >> 6;
  const int lane = tid & 63;
  const int cc = lane & 15;
  const int q = lane >> 4;
  const int n0 = blockIdx.x * 64;

  f32x4v acc1[8], acc2[8];
#pragma unroll
  for (int t = 0; t < 8; ++t) {
    acc1[t] = f32x4v{0.f, 0.f, 0.f, 0.f};
    acc2[t] = f32x4v{0.f, 0.f, 0.f, 0.f};
  }

  constexpr int KSTEPS = (K + 31) / 32;
  for (int ks = 0; ks < KSTEPS; ++ks) {
    int k0 = ks * 32;
    stage_X<float, K>(X, Xl, n0, k0, N, tid);
    stage_Wpre<KP>(WT1, Wt1, ks, tid);
    stage_Wpre<KP>(WT2, Wt2, ks, tid);
    __syncthreads();
    bf16x8v a = *(const bf16x8v*)&Xl[(w * 16 + cc) * 20 + q * 4];
#pragma unroll
    for (int t = 0; t < 8; ++t) {
      bf16x8v b1 = *(const bf16x8v*)&Wt1[(t * 16 + cc) * 20 + q * 4];
      bf16x8v b2 = *(const bf16x8v*)&Wt2[(t * 16 + cc) * 20 + q * 4];
      acc1[t] = __builtin_amdgcn_mfma_f32_16x16x32_bf16(a, b1, acc1[t], 0, 0, 0);
      acc2[t] = __builtin_amdgcn_mfma_f32_16x16x32_bf16(a, b2, acc2[t], 0, 0, 0);
    }
    __syncthreads();
  }
#pragma unroll
  for (int r = 0; r < 4; ++r) {
    int n = n0 + w * 16 + q * 4 + r;
    if (n < N) {
#pragma unroll
      for (int t = 0; t < 8; ++t) {
        outA[(size_t)n * HF + t * 16 + cc] = __float2bfloat16(acc1[t][r]);
        outB[(size_t)n * HF + t * 16 + cc] = __float2bfloat16(acc2[t][r]);
      }
    }
  }
  scores_epilogue(acc1, attn_l, attn_r, el, er, n0, w, q, cc, N);
}

// ============================ CSR build ====================================
// hist + readout init; STORES each edge's within-bucket rank (atomic return).
__global__ __launch_bounds__(256) void hist_kernel(
    const int* __restrict__ dst, int* __restrict__ deg,
    int* __restrict__ rank, float* __restrict__ hsum,
    unsigned* __restrict__ hmax, int E, int g32) {
  int e = blockIdx.x * 256 + threadIdx.x;
  if (e < g32) {
    hsum[e] = 0.f;
    hmax[e] = NEG_INF_ENC;
  }
  if (e < E) rank[e] = atomicAdd(&deg[dst[e]], 1);
}

__global__ __launch_bounds__(256) void scan1_kernel(
    const int* __restrict__ deg, int* __restrict__ row_ptr,
    int* __restrict__ bsum, int N) {
  const int base = blockIdx.x * 2048;
  const int tbase = base + threadIdx.x * 8;
  int vals[8];
  int tsum = 0;
#pragma unroll
  for (int i = 0; i < 8; ++i) {
    int idx = tbase + i;
    vals[i] = (idx < N) ? deg[idx] : 0;
    tsum += vals[i];
  }
  const int lane = threadIdx.x & 63, wv = threadIdx.x >> 6;
  int incl = tsum;
#pragma unroll
  for (int off = 1; off < 64; off <<= 1) {
    int nv = __shfl_up(incl, off);
    if (lane >= off) incl += nv;
  }
  __shared__ int wsum[4];
  if (lane == 63) wsum[wv] = incl;
  __syncthreads();
  int woff = 0;
  for (int w = 0; w < wv; ++w) woff += wsum[w];
  int run = woff + incl - tsum;
#pragma unroll
  for (int i = 0; i < 8; ++i) {
    int idx = tbase + i;
    if (idx < N) row_ptr[idx] = run;
    run += vals[i];
  }
  if (threadIdx.x == 255) bsum[blockIdx.x] = woff + incl;
}

__global__ __launch_bounds__(64) void scan2_kernel(
    const int* __restrict__ bsum, int* __restrict__ bpre, int NB) {
  const int lane = threadIdx.x;
  int running = 0;
  for (int c = 0; c < NB; c += 64) {
    int v = (c + lane < NB) ? bsum[c + lane] : 0;
    int incl = v;
#pragma unroll
    for (int off = 1; off < 64; off <<= 1) {
      int nv = __shfl_up(incl, off);
      if (lane >= off) incl += nv;
    }
    if (c + lane < NB) bpre[c + lane] = running + incl - v;
    running += __shfl(incl, 63);
  }
}

__global__ __launch_bounds__(256) void scan3_kernel(
    int* __restrict__ row_ptr, const int* __restrict__ bpre, int N, int E) {
  int t = blockIdx.x * 256 + threadIdx.x;
  if (t < N) row_ptr[t] += bpre[t >> 11];
  if (t == 0) row_ptr[N] = E;
}

// Atomic-free scatter: position = row_ptr[dst] + rank (from hist).
__global__ __launch_bounds__(256) void scatter_kernel(
    const int* __restrict__ src, const int* __restrict__ dst,
    const int* __restrict__ row_ptr, const int* __restrict__ rank,
    int* __restrict__ ssorted, int E) {
  int e = blockIdx.x * 256 + threadIdx.x;
  if (e >= E) return;
  int d = dst[e];
  ssorted[row_ptr[d] + rank[e]] = src[e];
}

// ============ fused softmax + aggregate (single edge pass) =================
// [round-15 form] One wave per node; lane = cols (2l,2l+1), head h = lane>>4.
// 8-edge straight-line bursts, direct wave-uniform ssorted loads, predicated
// clamped 8-burst tail, unsigned saddr gathers, exp2 with pre-scaled scores.

#define E8_LOAD(i, e_)                                                      \
  int s##i = ssorted[e_];                                                   \
  float xl##i = el[(unsigned)s##i * HEADS + h];                             \
  unsigned fu##i = *(const unsigned*)&feat[(unsigned)s##i * HF + c2];
#define E8_LOADC(i, e_)                                                     \
  int s##i = ssorted[min(e_, re - 1)];                                      \
  float xl##i = el[(unsigned)s##i * HEADS + h];                             \
  unsigned fu##i = *(const unsigned*)&feat[(unsigned)s##i * HF + c2];
#define E8_CALC(i)                                                          \
  {                                                                         \
    float xx = __builtin_amdgcn_exp2f(lrelu(xl##i + ern));                  \
    float2 ff = unpack_bf16(fu##i);                                         \
    ssum += xx;                                                             \
    ax = fmaf(xx, ff.x, ax);                                                \
    ay = fmaf(xx, ff.y, ay);                                                \
  }
#define E8_CALC_PRED(i, e_)                                                 \
  {                                                                         \
    float xx = __builtin_amdgcn_exp2f(lrelu(xl##i + ern));                  \
    xx = ((e_) + i < re) ? xx : 0.f;                                        \
    float2 ff = unpack_bf16(fu##i);                                         \
    ssum += xx;                                                             \
    ax = fmaf(xx, ff.x, ax);                                                \
    ay = fmaf(xx, ff.y, ay);                                                \
  }

#define AGG_LOOP                                                            \
  float ax = 0.f, ay = 0.f, ssum = 0.f;                                     \
  int e = rb;                                                               \
  for (; e + 8 <= re; e += 8) {                                             \
    E8_LOAD(0, e) E8_LOAD(1, e + 1) E8_LOAD(2, e + 2) E8_LOAD(3, e + 3)     \
    E8_LOAD(4, e + 4) E8_LOAD(5, e + 5) E8_LOAD(6, e + 6) E8_LOAD(7, e + 7) \
    E8_CALC(0) E8_CALC(1) E8_CALC(2) E8_CALC(3)                             \
    E8_CALC(4) E8_CALC(5) E8_CALC(6) E8_CALC(7)                             \
  }                                                                         \
  if (e < re) {                                                             \
    E8_LOADC(0, e) E8_LOADC(1, e + 1) E8_LOADC(2, e + 2)                    \
    E8_LOADC(3, e + 3) E8_LOADC(4, e + 4) E8_LOADC(5, e + 5)                \
    E8_LOADC(6, e + 6) E8_LOADC(7, e + 7)                                   \
    E8_CALC_PRED(0, e) E8_CALC_PRED(1, e) E8_CALC_PRED(2, e)                \
    E8_CALC_PRED(3, e) E8_CALC_PRED(4, e) E8_CALC_PRED(5, e)                \
    E8_CALC_PRED(6, e) E8_CALC_PRED(7, e)                                   \
  }

// Layer 1 epilogue: H[n] = elu(inv*agg + res[n] + bias)   (res, H bf16)
__global__ __launch_bounds__(256) void agg1_fused(
    const int* __restrict__ row_ptr, const int* __restrict__ ssorted,
    const float* __restrict__ el, const float* __restrict__ er,
    const bf16* __restrict__ feat, const bf16* __restrict__ res,
    bf16* __restrict__ H, const float* __restrict__ bias, int N) {
  int n = blockIdx.x * 4 + (threadIdx.x >> 6);
  if (n >= N) return;
  const int lane = threadIdx.x & 63;
  const int c2 = lane * 2, h = lane >> 4;
  const int rb = row_ptr[n], re = row_ptr[n + 1];
  const float ern = er[(unsigned)n * HEADS + h];

  AGG_LOOP

  float inv = 1.f / ssum;
  float2 r = unpack_bf16(*(const unsigned*)&res[(unsigned)n * HF + c2]);
  float2 bi = *(const float2*)&bias[c2];
  float vx = fmaf(ax, inv, r.x + bi.x);
  float vy = fmaf(ay, inv, r.y + bi.y);
  vx = (vx > 0.f) ? vx : expm1f(vx);
  vy = (vy > 0.f) ? vy : expm1f(vy);
  *(unsigned*)&H[(unsigned)n * HF + c2] = pack_bf16(vx, vy);
}

// Layer 2 epilogue: head-mean -> sigmoid gate -> readout atomics.
__global__ __launch_bounds__(256) void agg2_fused(
    const int* __restrict__ row_ptr, const int* __restrict__ ssorted,
    const float* __restrict__ el, const float* __restrict__ er,
    const bf16* __restrict__ feat, const bf16* __restrict__ h1,
    const float* __restrict__ bias, const float* __restrict__ ww,
    const float* __restrict__ wb, const int* __restrict__ gids,
    float* __restrict__ hsum, unsigned* __restrict__ hmax, int N) {
  int n = blockIdx.x * 4 + (threadIdx.x >> 6);
  if (n >= N) return;
  const int lane = threadIdx.x & 63;
  const int c2 = lane * 2, h = lane >> 4;
  const int rb = row_ptr[n], re = row_ptr[n + 1];
  const float ern = er[(unsigned)n * HEADS + h];

  AGG_LOOP

  float inv = 1.f / ssum;
  float2 r = unpack_bf16(*(const unsigned*)&h1[(unsigned)n * HF + c2]);
  float2 bi = *(const float2*)&bias[c2];
  ax = fmaf(ax, inv, r.x + bi.x);
  ay = fmaf(ay, inv, r.y + bi.y);
#pragma unroll
  for (int off = 16; off < 64; off <<= 1) {
    ax += __shfl_xor(ax, off);
    ay += __shfl_xor(ay, off);
  }
  ax *= 0.25f;
  ay *= 0.25f;
  int c = c2 & 31;
  float d = fmaf(ax, ww[c], ay * ww[c + 1]);
#pragma unroll
  for (int off = 1; off < 16; off <<= 1) d += __shfl_xor(d, off);
  float wv = 1.f / (1.f + __expf(-(d + wb[0])));
  if (lane < 16) {
    int g = gids[n];
    atomicAdd(&hsum[g * OUTF + c], wv * ax);
    atomicAdd(&hsum[g * OUTF + c + 1], wv * ay);
    atomicMax(&hmax[g * OUTF + c], enc_f(ax));
    atomicMax(&hmax[g * OUTF + c + 1], enc_f(ay));
  }
}

// ============================ readout tail =================================
__global__ __launch_bounds__(256) void final_gemm_kernel(
    const float* __restrict__ hsum, const unsigned* __restrict__ hmax,
    const float* __restrict__ tw, const float* __restrict__ tb,
    float* __restrict__ out, int G) {
  __shared__ float tws[64 * PRED_DIM];
  for (int i = threadIdx.x; i < 64 * PRED_DIM; i += 256) tws[i] = tw[i];
  __syncthreads();
  int g = blockIdx.x * 2 + (threadIdx.x >> 7);
  int p = threadIdx.x & 127;
  if (g >= G) return;
  float acc = tb[p];
#pragma unroll
  for (int k = 0; k < OUTF; ++k)
    acc = fmaf(hsum[g * OUTF + k], tws[k * PRED_DIM + p], acc);
#pragma unroll
  for (int k = 0; k < OUTF; ++k)
    acc = fmaf(dec_f(hmax[g * OUTF + k]), tws[(OUTF + k) * PRED_DIM + p], acc);
  out[(size_t)g * PRED_DIM + p] = acc;
}

static inline int cdiv(long long a, int b) { return (int)((a + b - 1) / b); }

extern "C" void kernel_launch(void* const* d_in, const int* in_sizes, int n_in,
                              void* d_out, int out_size, void* d_ws,
                              size_t ws_size, hipStream_t stream) {
  const float* feats   = (const float*)d_in[0];
  const int*   src     = (const int*)d_in[1];
  const int*   dst     = (const int*)d_in[2];
  const int*   gids    = (const int*)d_in[3];
  const float* fc1_w   = (const float*)d_in[4];
  const float* attn_l1 = (const float*)d_in[5];
  const float* attn_r1 = (const float*)d_in[6];
  const float* res1_w  = (const float*)d_in[7];
  const float* bias1   = (const float*)d_in[8];
  const float* fc2_w   = (const float*)d_in[9];
  const float* attn_l2 = (const float*)d_in[10];
  const float* attn_r2 = (const float*)d_in[11];
  const float* bias2   = (const float*)d_in[12];
  const float* ww      = (const float*)d_in[13];
  const float* wb      = (const float*)d_in[14];
  const float* tw      = (const float*)d_in[15];
  const float* tb      = (const float*)d_in[16];
  float* out = (float*)d_out;

  const int N = in_sizes[0] / IN_FEATS;  // 100000
  const int E = in_sizes[1];             // 900000
  const int G = out_size / PRED_DIM;     // 2048
  const int NB = cdiv(N, 2048);

  // ---- workspace layout ----
  bf16* A = (bf16*)d_ws;                      // N*128 bf16 (feat1/feat2)
  bf16* B = A + (size_t)N * HF;               // N*128 bf16 (res1)
  bf16* H = B + (size_t)N * HF;               // N*128 bf16 (h1)
  float* el = (float*)(H + (size_t)N * HF);   // N*4
  float* er = el + (size_t)N * HEADS;         // N*4
  float* hsum = er + (size_t)N * HEADS;       // G*32
  unsigned* hmax = (unsigned*)(hsum + (size_t)G * OUTF);  // G*32
  int* deg     = (int*)(hmax + (size_t)G * OUTF);  // N
  int* row_ptr = deg + N;                          // N+1
  int* ssorted = row_ptr + (N + 1);                // E
  int* rank    = ssorted + E;                      // E
  int* bsum    = rank + E;                         // NB
  int* bpre    = bsum + NB;                        // NB
  unsigned* WT1 = (unsigned*)(bpre + NB);          // 128*KP1
  unsigned* WT2 = WT1 + 128 * KP1;                 // 128*KP1
  unsigned* WT3 = WT2 + 128 * KP1;                 // 128*KP2

  const int gblk = cdiv(N, 64);
  const int nwblk = cdiv(N, 4);

  // ===================== prep + CSR build =====================
  hipMemsetAsync(deg, 0, (size_t)N * sizeof(int), stream);
  prep_w<<<cdiv(128 * (KP1 + KP2), 256), 256, 0, stream>>>(
      fc1_w, res1_w, fc2_w, WT1, WT2, WT3);
  hist_kernel<<<cdiv(E, 256), 256, 0, stream>>>(dst, deg, rank, hsum, hmax, E,
                                                G * OUTF);
  scan1_kernel<<<NB, 256, 0, stream>>>(deg, row_ptr, bsum, N);
  scan2_kernel<<<1, 64, 0, stream>>>(bsum, bpre, NB);
  scan3_kernel<<<cdiv(N, 256), 256, 0, stream>>>(row_ptr, bpre, N, E);
  scatter_kernel<<<cdiv(E, 256), 256, 0, stream>>>(src, dst, row_ptr, rank,
                                                   ssorted, E);

  // ===================== Layer 1 =====================
  mfma_dual<IN_FEATS, KP1><<<gblk, 256, 0, stream>>>(
      feats, WT1, WT2, attn_l1, attn_r1, A, B, el, er, N);
  agg1_fused<<<nwblk, 256, 0, stream>>>(row_ptr, ssorted, el, er, A, B, H,
                                        bias1, N);

  // ===================== Layer 2 =====================
  mfma_gemm<HF, KP2, bf16><<<gblk, 256, 0, stream>>>(
      H, WT3, attn_l2, attn_r2, A, el, er, N);
  agg2_fused<<<nwblk, 256, 0, stream>>>(row_ptr, ssorted, el, er, A, H, bias2,
                                        ww, wb, gids, hsum, hmax, N);

  // ===================== Readout =====================
  final_gemm_kernel<<<cdiv(G, 2), 256, 0, stream>>>(hsum, hmax, tw, tb, out, G);
}

// Round 18
// 373.911 us; speedup vs baseline: 1.0566x; 1.0114x over previous
//
#include <hip/hip_runtime.h>
#include <hip/hip_bf16.h>

// ---------------------------------------------------------------------------
// DGL GAT (2-layer, heads=4, out=32) + WeightedSumAndMax readout.
// Round 17: degree-specialized agg paths (wave-uniform branch):
//           deg<=8 -> single predicated 8-burst; deg<=16 -> single
//           straight-line 16-burst (all 34 loads in flight, 1 serial round
//           instead of 2 — covers the 54% of nodes with deg 9..16);
//           deg>16 -> generic loop. Everything else frozen at round 16.
// ---------------------------------------------------------------------------

#define HEADS 4
#define OUTF 32
#define HF 128            // HEADS*OUTF
#define IN_FEATS 74
#define PRED_DIM 128
#define NEG_SLOPE 0.2f
#define NEG_INF_ENC 0x007fffffu   // enc_f(-inf)
#define LOG2E 1.4426950408889634f
#define KP1 48            // kpairs for K=74 (padded to 96)
#define KP2 64            // kpairs for K=128

typedef __hip_bfloat16 bf16;
typedef __hip_bfloat162 bf16x2;
typedef __attribute__((ext_vector_type(8))) short bf16x8v;  // 8 bf16, 4 VGPRs
typedef __attribute__((ext_vector_type(4))) float f32x4v;   // MFMA C/D

__device__ __forceinline__ unsigned enc_f(float f) {
  unsigned u = __float_as_uint(f);
  return (u & 0x80000000u) ? ~u : (u | 0x80000000u);
}
__device__ __forceinline__ float dec_f(unsigned k) {
  return (k & 0x80000000u) ? __uint_as_float(k & 0x7fffffffu)
                           : __uint_as_float(~k);
}
__device__ __forceinline__ unsigned pack_bf16(float a, float b) {
  bf16x2 h = __float22bfloat162_rn(make_float2(a, b));
  return *(unsigned*)&h;
}
__device__ __forceinline__ float2 unpack_bf16(unsigned u) {
  bf16x2 h = *(bf16x2*)&u;
  return __bfloat1622float2(h);
}
__device__ __forceinline__ float lrelu(float v) {
  return fmaxf(v, NEG_SLOPE * v);
}

// ================= weight pre-pack (once per call) =========================
__global__ __launch_bounds__(256) void prep_w(
    const float* __restrict__ W1, const float* __restrict__ W2,
    const float* __restrict__ W3, unsigned* __restrict__ WT1,
    unsigned* __restrict__ WT2, unsigned* __restrict__ WT3) {
  int t = blockIdx.x * 256 + threadIdx.x;
  if (t < 128 * KP1) {
    int c = t / KP1, kp = t % KP1;
    int k = kp * 2;
    float a1 = (k < IN_FEATS) ? W1[k * HF + c] : 0.f;
    float b1 = (k + 1 < IN_FEATS) ? W1[(k + 1) * HF + c] : 0.f;
    float a2 = (k < IN_FEATS) ? W2[k * HF + c] : 0.f;
    float b2 = (k + 1 < IN_FEATS) ? W2[(k + 1) * HF + c] : 0.f;
    WT1[t] = pack_bf16(a1, b1);
    WT2[t] = pack_bf16(a2, b2);
  } else {
    int u = t - 128 * KP1;
    if (u < 128 * KP2) {
      int c = u / KP2, kp = u % KP2;
      int k = kp * 2;
      WT3[u] = pack_bf16(W3[k * HF + c], W3[(k + 1) * HF + c]);
    }
  }
}

// ===================== MFMA node GEMM building blocks ======================
template <typename XT, int K>
__device__ __forceinline__ void stage_X(const XT* __restrict__ X,
                                        unsigned* Xl, int n0, int k0, int N,
                                        int tid) {
  int n = tid >> 2;
  int kp0 = (tid & 3) * 4;
  int gn = n0 + n;
  uint4 val = make_uint4(0u, 0u, 0u, 0u);
  if (gn < N) {
    if (sizeof(XT) == 4) {
      const float* Xf = (const float*)X;
      unsigned v[4];
#pragma unroll
      for (int j = 0; j < 4; ++j) {
        int k = k0 + (kp0 + j) * 2;
        float2 xv = make_float2(0.f, 0.f);
        if (k < K) xv = *(const float2*)&Xf[(size_t)gn * K + k];
        v[j] = pack_bf16(xv.x, xv.y);
      }
      val = make_uint4(v[0], v[1], v[2], v[3]);
    } else {
      const unsigned* Xu = (const unsigned*)X;
      val = *(const uint4*)&Xu[((size_t)gn * K + k0) / 2 + kp0];
    }
  }
  *(uint4*)&Xl[n * 20 + kp0] = val;
}

template <int KP>
__device__ __forceinline__ void stage_Wpre(const unsigned* __restrict__ WT,
                                           unsigned* Wt, int ks, int tid) {
#pragma unroll
  for (int i = 0; i < 8; ++i) {
    int c = tid & 127;
    int kp = i * 2 + (tid >> 7);
    Wt[c * 20 + kp] = WT[c * KP + ks * 16 + kp];
  }
}

__device__ __forceinline__ void scores_epilogue(
    const f32x4v* acc, const float* __restrict__ attn_l,
    const float* __restrict__ attn_r, float* __restrict__ el,
    float* __restrict__ er, int n0, int w, int q, int cc, int N) {
#pragma unroll
  for (int r = 0; r < 4; ++r) {
    int n = n0 + w * 16 + q * 4 + r;
    float pls[4], prs[4];
#pragma unroll
    for (int h = 0; h < 4; ++h) {
      float pl = acc[2 * h][r] * attn_l[h * 32 + cc] +
                 acc[2 * h + 1][r] * attn_l[h * 32 + 16 + cc];
      float pr = acc[2 * h][r] * attn_r[h * 32 + cc] +
                 acc[2 * h + 1][r] * attn_r[h * 32 + 16 + cc];
#pragma unroll
      for (int off = 1; off < 16; off <<= 1) {
        pl += __shfl_xor(pl, off);
        pr += __shfl_xor(pr, off);
      }
      pls[h] = pl;
      prs[h] = pr;
    }
    if (cc == 0 && n < N) {
#pragma unroll
      for (int h = 0; h < 4; ++h) {
        el[n * HEADS + h] = pls[h] * LOG2E;
        er[n * HEADS + h] = prs[h] * LOG2E;
      }
    }
  }
}

template <int K, int KP, typename XT>
__global__ __launch_bounds__(256) void mfma_gemm(
    const XT* __restrict__ X, const unsigned* __restrict__ WT,
    const float* __restrict__ attn_l, const float* __restrict__ attn_r,
    bf16* __restrict__ out, float* __restrict__ el, float* __restrict__ er,
    int N) {
  __shared__ __align__(16) unsigned Xl[64 * 20];
  __shared__ __align__(16) unsigned Wt[128 * 20];
  const int tid = threadIdx.x;
  const int w = tid >> 6;
  const int lane = tid & 63;
  const int cc = lane & 15;
  const int q = lane >> 4;
  const int n0 = blockIdx.x * 64;

  f32x4v acc[8];
#pragma unroll
  for (int t = 0; t < 8; ++t) acc[t] = f32x4v{0.f, 0.f, 0.f, 0.f};

  constexpr int KSTEPS = (K + 31) / 32;
  for (int ks = 0; ks < KSTEPS; ++ks) {
    int k0 = ks * 32;
    stage_X<XT, K>(X, Xl, n0, k0, N, tid);
    stage_Wpre<KP>(WT, Wt, ks, tid);
    __syncthreads();
    bf16x8v a = *(const bf16x8v*)&Xl[(w * 16 + cc) * 20 + q * 4];
#pragma unroll
    for (int t = 0; t < 8; ++t) {
      bf16x8v b = *(const bf16x8v*)&Wt[(t * 16 + cc) * 20 + q * 4];
      acc[t] = __builtin_amdgcn_mfma_f32_16x16x32_bf16(a, b, acc[t], 0, 0, 0);
    }
    __syncthreads();
  }
#pragma unroll
  for (int r = 0; r < 4; ++r) {
    int n = n0 + w * 16 + q * 4 + r;
    if (n < N) {
#pragma unroll
      for (int t = 0; t < 8; ++t)
        out[(size_t)n * HF + t * 16 + cc] = __float2bfloat16(acc[t][r]);
    }
  }
  scores_epilogue(acc, attn_l, attn_r, el, er, n0, w, q, cc, N);
}

template <int K, int KP>
__global__ __launch_bounds__(256) void mfma_dual(
    const float* __restrict__ X, const unsigned* __restrict__ WT1,
    const unsigned* __restrict__ WT2, const float* __restrict__ attn_l,
    const float* __restrict__ attn_r, bf16* __restrict__ outA,
    bf16* __restrict__ outB, float* __restrict__ el, float* __restrict__ er,
    int N) {
  __shared__ __align__(16) unsigned Xl[64 * 20];
  __shared__ __align__(16) unsigned Wt1[128 * 20];
  __shared__ __align__(16) unsigned Wt2[128 * 20];
  const int tid = threadIdx.x;
  const int w = tid >> 6;
  const int lane = tid & 63;
  const int cc = lane & 15;
  const int q = lane >> 4;
  const int n0 = blockIdx.x * 64;

  f32x4v acc1[8], acc2[8];
#pragma unroll
  for (int t = 0; t < 8; ++t) {
    acc1[t] = f32x4v{0.f, 0.f, 0.f, 0.f};
    acc2[t] = f32x4v{0.f, 0.f, 0.f, 0.f};
  }

  constexpr int KSTEPS = (K + 31) / 32;
  for (int ks = 0; ks < KSTEPS; ++ks) {
    int k0 = ks * 32;
    stage_X<float, K>(X, Xl, n0, k0, N, tid);
    stage_Wpre<KP>(WT1, Wt1, ks, tid);
    stage_Wpre<KP>(WT2, Wt2, ks, tid);
    __syncthreads();
    bf16x8v a = *(const bf16x8v*)&Xl[(w * 16 + cc) * 20 + q * 4];
#pragma unroll
    for (int t = 0; t < 8; ++t) {
      bf16x8v b1 = *(const bf16x8v*)&Wt1[(t * 16 + cc) * 20 + q * 4];
      bf16x8v b2 = *(const bf16x8v*)&Wt2[(t * 16 + cc) * 20 + q * 4];
      acc1[t] = __builtin_amdgcn_mfma_f32_16x16x32_bf16(a, b1, acc1[t], 0, 0, 0);
      acc2[t] = __builtin_amdgcn_mfma_f32_16x16x32_bf16(a, b2, acc2[t], 0, 0, 0);
    }
    __syncthreads();
  }
#pragma unroll
  for (int r = 0; r < 4; ++r) {
    int n = n0 + w * 16 + q * 4 + r;
    if (n < N) {
#pragma unroll
      for (int t = 0; t < 8; ++t) {
        outA[(size_t)n * HF + t * 16 + cc] = __float2bfloat16(acc1[t][r]);
        outB[(size_t)n * HF + t * 16 + cc] = __float2bfloat16(acc2[t][r]);
      }
    }
  }
  scores_epilogue(acc1, attn_l, attn_r, el, er, n0, w, q, cc, N);
}

// ============================ CSR build ====================================
__global__ __launch_bounds__(256) void hist_kernel(
    const int* __restrict__ dst, int* __restrict__ deg,
    int* __restrict__ rank, float* __restrict__ hsum,
    unsigned* __restrict__ hmax, int E, int g32) {
  int e = blockIdx.x * 256 + threadIdx.x;
  if (e < g32) {
    hsum[e] = 0.f;
    hmax[e] = NEG_INF_ENC;
  }
  if (e < E) rank[e] = atomicAdd(&deg[dst[e]], 1);
}

__global__ __launch_bounds__(256) void scan1_kernel(
    const int* __restrict__ deg, int* __restrict__ row_ptr,
    int* __restrict__ bsum, int N) {
  const int base = blockIdx.x * 2048;
  const int tbase = base + threadIdx.x * 8;
  int vals[8];
  int tsum = 0;
#pragma unroll
  for (int i = 0; i < 8; ++i) {
    int idx = tbase + i;
    vals[i] = (idx < N) ? deg[idx] : 0;
    tsum += vals[i];
  }
  const int lane = threadIdx.x & 63, wv = threadIdx.x >> 6;
  int incl = tsum;
#pragma unroll
  for (int off = 1; off < 64; off <<= 1) {
    int nv = __shfl_up(incl, off);
    if (lane >= off) incl += nv;
  }
  __shared__ int wsum[4];
  if (lane == 63) wsum[wv] = incl;
  __syncthreads();
  int woff = 0;
  for (int w = 0; w < wv; ++w) woff += wsum[w];
  int run = woff + incl - tsum;
#pragma unroll
  for (int i = 0; i < 8; ++i) {
    int idx = tbase + i;
    if (idx < N) row_ptr[idx] = run;
    run += vals[i];
  }
  if (threadIdx.x == 255) bsum[blockIdx.x] = woff + incl;
}

__global__ __launch_bounds__(64) void scan2_kernel(
    const int* __restrict__ bsum, int* __restrict__ bpre, int NB) {
  const int lane = threadIdx.x;
  int running = 0;
  for (int c = 0; c < NB; c += 64) {
    int v = (c + lane < NB) ? bsum[c + lane] : 0;
    int incl = v;
#pragma unroll
    for (int off = 1; off < 64; off <<= 1) {
      int nv = __shfl_up(incl, off);
      if (lane >= off) incl += nv;
    }
    if (c + lane < NB) bpre[c + lane] = running + incl - v;
    running += __shfl(incl, 63);
  }
}

__global__ __launch_bounds__(256) void scan3_kernel(
    int* __restrict__ row_ptr, const int* __restrict__ bpre, int N, int E) {
  int t = blockIdx.x * 256 + threadIdx.x;
  if (t < N) row_ptr[t] += bpre[t >> 11];
  if (t == 0) row_ptr[N] = E;
}

__global__ __launch_bounds__(256) void scatter_kernel(
    const int* __restrict__ src, const int* __restrict__ dst,
    const int* __restrict__ row_ptr, const int* __restrict__ rank,
    int* __restrict__ ssorted, int E) {
  int e = blockIdx.x * 256 + threadIdx.x;
  if (e >= E) return;
  int d = dst[e];
  ssorted[row_ptr[d] + rank[e]] = src[e];
}

// ============ fused softmax + aggregate (single edge pass) =================
// One wave per node; lane holds cols (2*lane, 2*lane+1), head h = lane>>4.
// Degree-specialized (wave-uniform): deg<=8 one predicated 8-burst;
// deg<=16 one straight-line 16-burst (all loads before any calc);
// else generic 8-burst loop + predicated tail.

#define E8_LOAD(i, e_)                                                      \
  int s##i = ssorted[e_];                                                   \
  float xl##i = el[(unsigned)s##i * HEADS + h];                             \
  unsigned fu##i = *(const unsigned*)&feat[(unsigned)s##i * HF + c2];
#define E8_LOADC(i, e_)                                                     \
  int s##i = ssorted[min(e_, re - 1)];                                      \
  float xl##i = el[(unsigned)s##i * HEADS + h];                             \
  unsigned fu##i = *(const unsigned*)&feat[(unsigned)s##i * HF + c2];
#define E8_CALC(i)                                                          \
  {                                                                         \
    float xx = __builtin_amdgcn_exp2f(lrelu(xl##i + ern));                  \
    float2 ff = unpack_bf16(fu##i);                                         \
    ssum += xx;                                                             \
    ax = fmaf(xx, ff.x, ax);                                                \
    ay = fmaf(xx, ff.y, ay);                                                \
  }
#define E8_CALC_PRED(i, e_)                                                 \
  {                                                                         \
    float xx = __builtin_amdgcn_exp2f(lrelu(xl##i + ern));                  \
    xx = ((e_) + i < re) ? xx : 0.f;                                        \
    float2 ff = unpack_bf16(fu##i);                                         \
    ssum += xx;                                                             \
    ax = fmaf(xx, ff.x, ax);                                                \
    ay = fmaf(xx, ff.y, ay);                                                \
  }

#define AGG_LOOP                                                            \
  float ax = 0.f, ay = 0.f, ssum = 0.f;                                     \
  const int dg = re - rb;                                                   \
  if (dg <= 8) {                                                            \
    E8_LOADC(0, rb) E8_LOADC(1, rb + 1) E8_LOADC(2, rb + 2)                 \
    E8_LOADC(3, rb + 3) E8_LOADC(4, rb + 4) E8_LOADC(5, rb + 5)             \
    E8_LOADC(6, rb + 6) E8_LOADC(7, rb + 7)                                 \
    E8_CALC_PRED(0, rb) E8_CALC_PRED(1, rb) E8_CALC_PRED(2, rb)             \
    E8_CALC_PRED(3, rb) E8_CALC_PRED(4, rb) E8_CALC_PRED(5, rb)             \
    E8_CALC_PRED(6, rb) E8_CALC_PRED(7, rb)                                 \
  } else if (dg <= 16) {                                                    \
    E8_LOAD(0, rb) E8_LOAD(1, rb + 1) E8_LOAD(2, rb + 2)                    \
    E8_LOAD(3, rb + 3) E8_LOAD(4, rb + 4) E8_LOAD(5, rb + 5)                \
    E8_LOAD(6, rb + 6) E8_LOAD(7, rb + 7)                                   \
    E8_LOADC(8, rb + 8) E8_LOADC(9, rb + 9) E8_LOADC(10, rb + 10)           \
    E8_LOADC(11, rb + 11) E8_LOADC(12, rb + 12) E8_LOADC(13, rb + 13)       \
    E8_LOADC(14, rb + 14) E8_LOADC(15, rb + 15)                             \
    E8_CALC(0) E8_CALC(1) E8_CALC(2) E8_CALC(3)                             \
    E8_CALC(4) E8_CALC(5) E8_CALC(6) E8_CALC(7)                             \
    E8_CALC_PRED(8, rb) E8_CALC_PRED(9, rb) E8_CALC_PRED(10, rb)            \
    E8_CALC_PRED(11, rb) E8_CALC_PRED(12, rb) E8_CALC_PRED(13, rb)          \
    E8_CALC_PRED(14, rb) E8_CALC_PRED(15, rb)                               \
  } else {                                                                  \
    int e = rb;                                                             \
    for (; e + 8 <= re; e += 8) {                                           \
      E8_LOAD(0, e) E8_LOAD(1, e + 1) E8_LOAD(2, e + 2) E8_LOAD(3, e + 3)   \
      E8_LOAD(4, e + 4) E8_LOAD(5, e + 5) E8_LOAD(6, e + 6)                 \
      E8_LOAD(7, e + 7)                                                     \
      E8_CALC(0) E8_CALC(1) E8_CALC(2) E8_CALC(3)                           \
      E8_CALC(4) E8_CALC(5) E8_CALC(6) E8_CALC(7)                           \
    }                                                                       \
    if (e < re) {                                                           \
      E8_LOADC(0, e) E8_LOADC(1, e + 1) E8_LOADC(2, e + 2)                  \
      E8_LOADC(3, e + 3) E8_LOADC(4, e + 4) E8_LOADC(5, e + 5)              \
      E8_LOADC(6, e + 6) E8_LOADC(7, e + 7)                                 \
      E8_CALC_PRED(0, e) E8_CALC_PRED(1, e) E8_CALC_PRED(2, e)              \
      E8_CALC_PRED(3, e) E8_CALC_PRED(4, e) E8_CALC_PRED(5, e)              \
      E8_CALC_PRED(6, e) E8_CALC_PRED(7, e)                                 \
    }                                                                       \
  }

// Layer 1 epilogue: H[n] = elu(inv*agg + res[n] + bias)   (res, H bf16)
__global__ __launch_bounds__(256) void agg1_fused(
    const int* __restrict__ row_ptr, const int* __restrict__ ssorted,
    const float* __restrict__ el, const float* __restrict__ er,
    const bf16* __restrict__ feat, const bf16* __restrict__ res,
    bf16* __restrict__ H, const float* __restrict__ bias, int N) {
  int n = blockIdx.x * 4 + (threadIdx.x >> 6);
  if (n >= N) return;
  const int lane = threadIdx.x & 63;
  const int c2 = lane * 2, h = lane >> 4;
  const int rb = row_ptr[n], re = row_ptr[n + 1];
  const float ern = er[(unsigned)n * HEADS + h];

  AGG_LOOP

  float inv = 1.f / ssum;
  float2 r = unpack_bf16(*(const unsigned*)&res[(unsigned)n * HF + c2]);
  float2 bi = *(const float2*)&bias[c2];
  float vx = fmaf(ax, inv, r.x + bi.x);
  float vy = fmaf(ay, inv, r.y + bi.y);
  vx = (vx > 0.f) ? vx : expm1f(vx);
  vy = (vy > 0.f) ? vy : expm1f(vy);
  *(unsigned*)&H[(unsigned)n * HF + c2] = pack_bf16(vx, vy);
}

// Layer 2 epilogue: head-mean -> sigmoid gate -> readout atomics.
__global__ __launch_bounds__(256) void agg2_fused(
    const int* __restrict__ row_ptr, const int* __restrict__ ssorted,
    const float* __restrict__ el, const float* __restrict__ er,
    const bf16* __restrict__ feat, const bf16* __restrict__ h1,
    const float* __restrict__ bias, const float* __restrict__ ww,
    const float* __restrict__ wb, const int* __restrict__ gids,
    float* __restrict__ hsum, unsigned* __restrict__ hmax, int N) {
  int n = blockIdx.x * 4 + (threadIdx.x >> 6);
  if (n >= N) return;
  const int lane = threadIdx.x & 63;
  const int c2 = lane * 2, h = lane >> 4;
  const int rb = row_ptr[n], re = row_ptr[n + 1];
  const float ern = er[(unsigned)n * HEADS + h];

  AGG_LOOP

  float inv = 1.f / ssum;
  float2 r = unpack_bf16(*(const unsigned*)&h1[(unsigned)n * HF + c2]);
  float2 bi = *(const float2*)&bias[c2];
  ax = fmaf(ax, inv, r.x + bi.x);
  ay = fmaf(ay, inv, r.y + bi.y);
#pragma unroll
  for (int off = 16; off < 64; off <<= 1) {
    ax += __shfl_xor(ax, off);
    ay += __shfl_xor(ay, off);
  }
  ax *= 0.25f;
  ay *= 0.25f;
  int c = c2 & 31;
  float d = fmaf(ax, ww[c], ay * ww[c + 1]);
#pragma unroll
  for (int off = 1; off < 16; off <<= 1) d += __shfl_xor(d, off);
  float wv = 1.f / (1.f + __expf(-(d + wb[0])));
  if (lane < 16) {
    int g = gids[n];
    atomicAdd(&hsum[g * OUTF + c], wv * ax);
    atomicAdd(&hsum[g * OUTF + c + 1], wv * ay);
    atomicMax(&hmax[g * OUTF + c], enc_f(ax));
    atomicMax(&hmax[g * OUTF + c + 1], enc_f(ay));
  }
}

// ============================ readout tail =================================
__global__ __launch_bounds__(256) void final_gemm_kernel(
    const float* __restrict__ hsum, const unsigned* __restrict__ hmax,
    const float* __restrict__ tw, const float* __restrict__ tb,
    float* __restrict__ out, int G) {
  __shared__ float tws[64 * PRED_DIM];
  for (int i = threadIdx.x; i < 64 * PRED_DIM; i += 256) tws[i] = tw[i];
  __syncthreads();
  int g = blockIdx.x * 2 + (threadIdx.x >> 7);
  int p = threadIdx.x & 127;
  if (g >= G) return;
  float acc = tb[p];
#pragma unroll
  for (int k = 0; k < OUTF; ++k)
    acc = fmaf(hsum[g * OUTF + k], tws[k * PRED_DIM + p], acc);
#pragma unroll
  for (int k = 0; k < OUTF; ++k)
    acc = fmaf(dec_f(hmax[g * OUTF + k]), tws[(OUTF + k) * PRED_DIM + p], acc);
  out[(size_t)g * PRED_DIM + p] = acc;
}

static inline int cdiv(long long a, int b) { return (int)((a + b - 1) / b); }

extern "C" void kernel_launch(void* const* d_in, const int* in_sizes, int n_in,
                              void* d_out, int out_size, void* d_ws,
                              size_t ws_size, hipStream_t stream) {
  const float* feats   = (const float*)d_in[0];
  const int*   src     = (const int*)d_in[1];
  const int*   dst     = (const int*)d_in[2];
  const int*   gids    = (const int*)d_in[3];
  const float* fc1_w   = (const float*)d_in[4];
  const float* attn_l1 = (const float*)d_in[5];
  const float* attn_r1 = (const float*)d_in[6];
  const float* res1_w  = (const float*)d_in[7];
  const float* bias1   = (const float*)d_in[8];
  const float* fc2_w   = (const float*)d_in[9];
  const float* attn_l2 = (const float*)d_in[10];
  const float* attn_r2 = (const float*)d_in[11];
  const float* bias2   = (const float*)d_in[12];
  const float* ww      = (const float*)d_in[13];
  const float* wb      = (const float*)d_in[14];
  const float* tw      = (const float*)d_in[15];
  const float* tb      = (const float*)d_in[16];
  float* out = (float*)d_out;

  const int N = in_sizes[0] / IN_FEATS;  // 100000
  const int E = in_sizes[1];             // 900000
  const int G = out_size / PRED_DIM;     // 2048
  const int NB = cdiv(N, 2048);

  // ---- workspace layout ----
  bf16* A = (bf16*)d_ws;                      // N*128 bf16 (feat1/feat2)
  bf16* B = A + (size_t)N * HF;               // N*128 bf16 (res1)
  bf16* H = B + (size_t)N * HF;               // N*128 bf16 (h1)
  float* el = (float*)(H + (size_t)N * HF);   // N*4
  float* er = el + (size_t)N * HEADS;         // N*4
  float* hsum = er + (size_t)N * HEADS;       // G*32
  unsigned* hmax = (unsigned*)(hsum + (size_t)G * OUTF);  // G*32
  int* deg     = (int*)(hmax + (size_t)G * OUTF);  // N
  int* row_ptr = deg + N;                          // N+1
  int* ssorted = row_ptr + (N + 1);                // E
  int* rank    = ssorted + E;                      // E
  int* bsum    = rank + E;                         // NB
  int* bpre    = bsum + NB;                        // NB
  unsigned* WT1 = (unsigned*)(bpre + NB);          // 128*KP1
  unsigned* WT2 = WT1 + 128 * KP1;                 // 128*KP1
  unsigned* WT3 = WT2 + 128 * KP1;                 // 128*KP2

  const int gblk = cdiv(N, 64);
  const int nwblk = cdiv(N, 4);

  // ===================== prep + CSR build =====================
  hipMemsetAsync(deg, 0, (size_t)N * sizeof(int), stream);
  prep_w<<<cdiv(128 * (KP1 + KP2), 256), 256, 0, stream>>>(
      fc1_w, res1_w, fc2_w, WT1, WT2, WT3);
  hist_kernel<<<cdiv(E, 256), 256, 0, stream>>>(dst, deg, rank, hsum, hmax, E,
                                                G * OUTF);
  scan1_kernel<<<NB, 256, 0, stream>>>(deg, row_ptr, bsum, N);
  scan2_kernel<<<1, 64, 0, stream>>>(bsum, bpre, NB);
  scan3_kernel<<<cdiv(N, 256), 256, 0, stream>>>(row_ptr, bpre, N, E);
  scatter_kernel<<<cdiv(E, 256), 256, 0, stream>>>(src, dst, row_ptr, rank,
                                                   ssorted, E);

  // ===================== Layer 1 =====================
  mfma_dual<IN_FEATS, KP1><<<gblk, 256, 0, stream>>>(
      feats, WT1, WT2, attn_l1, attn_r1, A, B, el, er, N);
  agg1_fused<<<nwblk, 256, 0, stream>>>(row_ptr, ssorted, el, er, A, B, H,
                                        bias1, N);

  // ===================== Layer 2 =====================
  mfma_gemm<HF, KP2, bf16><<<gblk, 256, 0, stream>>>(
      H, WT3, attn_l2, attn_r2, A, el, er, N);
  agg2_fused<<<nwblk, 256, 0, stream>>>(row_ptr, ssorted, el, er, A, H, bias2,
                                        ww, wb, gids, hsum, hmax, N);

  // ===================== Readout =====================
  final_gemm_kernel<<<cdiv(G, 2), 256, 0, stream>>>(hsum, hmax, tw, tb, out, G);
}